// Round 1
// baseline (4501.414 us; speedup 1.0000x reference)
//
#include <hip/hip_runtime.h>

#define N_NODES 100000
#define N_EDGES 1600000
#define D 128

// ---------------------------------------------------------------------------
// degree count (push): deg_s[src]++ , deg_d[dst]++
__global__ void k_degree(const int* __restrict__ src, const int* __restrict__ dst,
                         float* __restrict__ deg_s, float* __restrict__ deg_d) {
    int i = blockIdx.x * blockDim.x + threadIdx.x;
    int stride = gridDim.x * blockDim.x;
    for (; i < N_EDGES; i += stride) {
        unsafeAtomicAdd(&deg_s[src[i]], 1.0f);
        unsafeAtomicAdd(&deg_d[dst[i]], 1.0f);
    }
}

// norm = rsqrt(max(deg,1)) in place over both ns and nd (2N contiguous)
__global__ void k_norm(float* __restrict__ deg) {
    int i = blockIdx.x * blockDim.x + threadIdx.x;
    if (i < 2 * N_NODES) deg[i] = rsqrtf(fmaxf(deg[i], 1.0f));
}

// out[n][:] = x[n][:] * ns[n]   (float4 vectorized)
__global__ void k_scale_rows(const float* __restrict__ x, const float* __restrict__ ns,
                             float* __restrict__ out) {
    int i = blockIdx.x * blockDim.x + threadIdx.x;  // over N*D/4 float4s
    if (i >= N_NODES * (D / 4)) return;
    int n = i >> 5;  // (i*4)/128
    float4 v = ((const float4*)x)[i];
    float s = ns[n];
    v.x *= s; v.y *= s; v.z *= s; v.w *= s;
    ((float4*)out)[i] = v;
}

// push SpMM: agg[dst[e]][:] += x[src[e]][:]   (x is pre-scaled by norm_src)
// one wave per edge iteration; lane handles 2 consecutive floats (float2 load)
__global__ void k_spmm(const float* __restrict__ x, const int* __restrict__ src,
                       const int* __restrict__ dst, float* __restrict__ agg) {
    int gid = blockIdx.x * blockDim.x + threadIdx.x;
    int wave = gid >> 6;
    int lane = threadIdx.x & 63;
    int nw = (gridDim.x * blockDim.x) >> 6;
    for (int e = wave; e < N_EDGES; e += nw) {
        int s = src[e];
        int d = dst[e];
        float2 v = ((const float2*)(x + (size_t)s * D))[lane];
        float* ar = agg + (size_t)d * D + 2 * lane;
        unsafeAtomicAdd(ar, v.x);
        unsafeAtomicAdd(ar + 1, v.y);
    }
}

// out[n][j] = epilogue( nd[n] * sum_k A[n][k]*W[k][j] + b[j] )
// epilogue (relu path): relu(.) * ns[n]  -> pre-scaled input for next layer
// 64-row x 128-col tile per block, 256 threads, 2x16 register blocking.
// LDS: As 32KB (swizzled, conflict-free) + Ws 32KB (k-half, 2 phases) = 64KB.
__global__ __launch_bounds__(256) void
k_gemm(const float* __restrict__ A, const float* __restrict__ W,
       const float* __restrict__ b, const float* __restrict__ nd,
       const float* __restrict__ ns, float* __restrict__ out) {
    __shared__ float As[64][128];  // As[r][(c + r) & 127] = A[row0+r][c]
    __shared__ float Ws[64][128];  // k-half chunk
    int tid = threadIdx.x;
    int row0 = blockIdx.x * 64;

    for (int i = tid; i < 64 * 128; i += 256) {
        int r = i >> 7, c = i & 127;
        int n = row0 + r;
        As[r][(c + r) & 127] = (n < N_NODES) ? A[(size_t)n * D + c] : 0.0f;
    }

    int r = tid >> 3;          // 0..31 (also handles r+32)
    int c4 = (tid & 7) * 4;    // column base; cols = c4 + 32*g + q
    float acc[2][16];
#pragma unroll
    for (int h = 0; h < 2; h++)
#pragma unroll
        for (int j = 0; j < 16; j++) acc[h][j] = 0.0f;

    for (int ph = 0; ph < 2; ph++) {
        __syncthreads();  // protect Ws reuse (and As readiness on ph 0 via next barrier)
        for (int i = tid; i < 64 * 128; i += 256)
            Ws[i >> 7][i & 127] = W[(size_t)(ph * 64 + (i >> 7)) * D + (i & 127)];
        __syncthreads();
#pragma unroll 4
        for (int kk = 0; kk < 64; kk++) {
            int k = ph * 64 + kk;
            float a0 = As[r][(k + r) & 127];
            float a1 = As[r + 32][(k + r + 32) & 127];
#pragma unroll
            for (int g = 0; g < 4; g++) {
                float4 w = *(const float4*)&Ws[kk][c4 + 32 * g];
                acc[0][g * 4 + 0] = fmaf(a0, w.x, acc[0][g * 4 + 0]);
                acc[0][g * 4 + 1] = fmaf(a0, w.y, acc[0][g * 4 + 1]);
                acc[0][g * 4 + 2] = fmaf(a0, w.z, acc[0][g * 4 + 2]);
                acc[0][g * 4 + 3] = fmaf(a0, w.w, acc[0][g * 4 + 3]);
                acc[1][g * 4 + 0] = fmaf(a1, w.x, acc[1][g * 4 + 0]);
                acc[1][g * 4 + 1] = fmaf(a1, w.y, acc[1][g * 4 + 1]);
                acc[1][g * 4 + 2] = fmaf(a1, w.z, acc[1][g * 4 + 2]);
                acc[1][g * 4 + 3] = fmaf(a1, w.w, acc[1][g * 4 + 3]);
            }
        }
    }

#pragma unroll
    for (int h = 0; h < 2; h++) {
        int n = row0 + r + h * 32;
        if (n >= N_NODES) continue;
        float sd = nd[n];
        float ss = ns[n];
        float* orow = out + (size_t)n * D;
#pragma unroll
        for (int g = 0; g < 4; g++) {
            float4 v;
            float bx = b[c4 + 32 * g + 0], by = b[c4 + 32 * g + 1];
            float bz = b[c4 + 32 * g + 2], bw = b[c4 + 32 * g + 3];
            v.x = fmaxf(sd * acc[h][g * 4 + 0] + bx, 0.0f) * ss;
            v.y = fmaxf(sd * acc[h][g * 4 + 1] + by, 0.0f) * ss;
            v.z = fmaxf(sd * acc[h][g * 4 + 2] + bz, 0.0f) * ss;
            v.w = fmaxf(sd * acc[h][g * 4 + 3] + bw, 0.0f) * ss;
            *(float4*)(orow + c4 + 32 * g) = v;
        }
    }
}

// colsum[c] = sum_n nd[n] * agg[n][c]   (block-partial + 128 atomics/block)
__global__ void k_colsum(const float* __restrict__ agg, const float* __restrict__ nd,
                         float* __restrict__ colsum) {
    __shared__ float part[128];
    int t = threadIdx.x;
    int c = t & 127, half = t >> 7;
    int chunk = (N_NODES + gridDim.x - 1) / gridDim.x;
    int r0 = blockIdx.x * chunk;
    int r1 = min(r0 + chunk, N_NODES);
    float acc = 0.0f;
    for (int r = r0 + half; r < r1; r += 2)
        acc += nd[r] * agg[(size_t)r * D + c];
    if (half) part[c] = acc;
    __syncthreads();
    if (!half) unsafeAtomicAdd(&colsum[c], acc + part[c]);
}

// out[j] = (colsum/N) @ W2 [:,j] + b2[j]
__global__ void k_final(const float* __restrict__ colsum, const float* __restrict__ W,
                        const float* __restrict__ b, float* __restrict__ out) {
    __shared__ float m[128];
    int j = threadIdx.x;
    m[j] = colsum[j] * (1.0f / N_NODES);
    __syncthreads();
    float acc = b[j];
    for (int k = 0; k < 128; k++)
        acc = fmaf(m[k], W[(size_t)k * D + j], acc);
    out[j] = acc;
}

extern "C" void kernel_launch(void* const* d_in, const int* in_sizes, int n_in,
                              void* d_out, int out_size, void* d_ws, size_t ws_size,
                              hipStream_t stream) {
    const float* h   = (const float*)d_in[0];
    const int*   src = (const int*)d_in[1];
    const int*   dst = (const int*)d_in[2];
    const float* W0  = (const float*)d_in[3];
    const float* b0  = (const float*)d_in[4];
    const float* W1  = (const float*)d_in[5];
    const float* b1  = (const float*)d_in[6];
    const float* W2  = (const float*)d_in[7];
    const float* b2  = (const float*)d_in[8];
    float* out = (float*)d_out;

    float* ws     = (float*)d_ws;
    float* deg    = ws;                    // 2N floats: ns then nd
    float* ns     = ws;
    float* nd     = ws + N_NODES;
    float* colsum = ws + 2 * N_NODES;      // 128 floats
    float* bufA   = colsum + 128;          // N*D floats
    float* bufB   = bufA + (size_t)N_NODES * D;  // N*D floats

    // degrees -> norms
    hipMemsetAsync(deg, 0, 2 * N_NODES * sizeof(float), stream);
    k_degree<<<2048, 256, 0, stream>>>(src, dst, ns, nd);
    k_norm<<<(2 * N_NODES + 255) / 256, 256, 0, stream>>>(deg);

    // x0s = h * ns  (pre-scaled by norm_src)
    k_scale_rows<<<(N_NODES * (D / 4) + 255) / 256, 256, 0, stream>>>(h, ns, bufA);

    const float* Wl[3] = {W0, W1, W2};
    const float* bl[3] = {b0, b1, b2};
    for (int l = 0; l < 3; l++) {
        hipMemsetAsync(bufB, 0, (size_t)N_NODES * D * sizeof(float), stream);
        k_spmm<<<4096, 256, 0, stream>>>(bufA, src, dst, bufB);
        if (l < 2) {
            // bufA = relu(nd * (bufB @ W) + b) * ns   (pre-scaled for next layer)
            k_gemm<<<(N_NODES + 63) / 64, 256, 0, stream>>>(bufB, Wl[l], bl[l], nd, ns, bufA);
        } else {
            // out = (mean_n nd[n]*bufB[n]) @ W2 + b2
            hipMemsetAsync(colsum, 0, 128 * sizeof(float), stream);
            k_colsum<<<256, 256, 0, stream>>>(bufB, nd, colsum);
            k_final<<<1, 128, 0, stream>>>(colsum, W2, b2, out);
        }
    }
}

// Round 2
// 1002.767 us; speedup vs baseline: 4.4890x; 4.4890x over previous
//
#include <hip/hip_runtime.h>

#define N_NODES 100000
#define N_EDGES 1600000
#define D 128
#define SCAN_NB ((N_NODES + 1023) / 1024)   // 98

// ---------------------------------------------------------------------------
// histogram: cnt_src[src]++ , cnt_dst[dst]++   (int atomics)
__global__ void k_hist(const int* __restrict__ src, const int* __restrict__ dst,
                       int* __restrict__ cnt_src, int* __restrict__ cnt_dst) {
    int i = blockIdx.x * blockDim.x + threadIdx.x;
    int stride = gridDim.x * blockDim.x;
    for (; i < N_EDGES; i += stride) {
        atomicAdd(&cnt_src[src[i]], 1);
        atomicAdd(&cnt_dst[dst[i]], 1);
    }
}

// block-local inclusive scan of cnt (1024/block) -> rp1[i]; block totals -> blkSums
__global__ __launch_bounds__(1024) void
k_scan1(const int* __restrict__ cnt, int* __restrict__ rp1, int* __restrict__ blkSums) {
    __shared__ int s[1024];
    int tid = threadIdx.x;
    int i = blockIdx.x * 1024 + tid;
    int v = (i < N_NODES) ? cnt[i] : 0;
    s[tid] = v;
    __syncthreads();
    for (int d = 1; d < 1024; d <<= 1) {
        int t = (tid >= d) ? s[tid - d] : 0;
        __syncthreads();
        s[tid] += t;
        __syncthreads();
    }
    if (i < N_NODES) rp1[i] = s[tid];
    if (tid == 1023) blkSums[blockIdx.x] = s[1023];
}

// scan the 98 block sums -> exclusive offsets (in place)
__global__ void k_scan2(int* __restrict__ blkSums) {
    __shared__ int s[128];
    int tid = threadIdx.x;
    int v = (tid < SCAN_NB) ? blkSums[tid] : 0;
    s[tid] = v;
    __syncthreads();
    for (int d = 1; d < 128; d <<= 1) {
        int t = (tid >= d) ? s[tid - d] : 0;
        __syncthreads();
        s[tid] += t;
        __syncthreads();
    }
    if (tid < SCAN_NB) blkSums[tid] = s[tid] - v;  // exclusive
}

// finalize: row_ptr (exclusive, N+1) and cursor[i] = row_ptr[i]
__global__ void k_scan3(const int* __restrict__ cnt, int* __restrict__ row_ptr,
                        int* __restrict__ cursor, const int* __restrict__ blkSums) {
    int i = blockIdx.x * blockDim.x + threadIdx.x;
    if (i >= N_NODES) return;
    int v = row_ptr[1 + i] + blkSums[i >> 10];  // global inclusive
    row_ptr[1 + i] = v;
    cursor[i] = v - cnt[i];
    if (i == 0) row_ptr[0] = 0;
}

// norms from int degree counts
__global__ void k_norm2(const int* __restrict__ cnt_src, const int* __restrict__ cnt_dst,
                        float* __restrict__ ns, float* __restrict__ nd) {
    int i = blockIdx.x * blockDim.x + threadIdx.x;
    if (i >= N_NODES) return;
    ns[i] = rsqrtf((float)max(cnt_src[i], 1));
    nd[i] = rsqrtf((float)max(cnt_dst[i], 1));
}

// scatter edges into CSR buckets
__global__ void k_scatter(const int* __restrict__ src, const int* __restrict__ dst,
                          int* __restrict__ cursor, int* __restrict__ csr_src) {
    int i = blockIdx.x * blockDim.x + threadIdx.x;
    int stride = gridDim.x * blockDim.x;
    for (; i < N_EDGES; i += stride) {
        int pos = atomicAdd(&cursor[dst[i]], 1);
        csr_src[pos] = src[i];
    }
}

// out[n][:] = x[n][:] * ns[n]   (float4 vectorized)
__global__ void k_scale_rows(const float* __restrict__ x, const float* __restrict__ ns,
                             float* __restrict__ out) {
    int i = blockIdx.x * blockDim.x + threadIdx.x;  // over N*D/4 float4s
    if (i >= N_NODES * (D / 4)) return;
    int n = i >> 5;  // (i*4)/128
    float4 v = ((const float4*)x)[i];
    float s = ns[n];
    v.x *= s; v.y *= s; v.z *= s; v.w *= s;
    ((float4*)out)[i] = v;
}

// pull SpMM: agg[n][:] = sum_{e in-edges of n} x[csr_src[e]][:]
// one wave per node; lane holds float2 (cols 2*lane, 2*lane+1); no atomics.
__global__ __launch_bounds__(256) void
k_spmm_pull(const float* __restrict__ x, const int* __restrict__ row_ptr,
            const int* __restrict__ csr_src, float* __restrict__ agg) {
    int wave = (blockIdx.x * blockDim.x + threadIdx.x) >> 6;
    int lane = threadIdx.x & 63;
    if (wave >= N_NODES) return;
    int beg = row_ptr[wave], end = row_ptr[wave + 1];
    float accx = 0.0f, accy = 0.0f;
    int j = beg;
    for (; j + 3 < end; j += 4) {
        int s0 = csr_src[j], s1 = csr_src[j + 1];
        int s2 = csr_src[j + 2], s3 = csr_src[j + 3];
        float2 v0 = ((const float2*)(x + (size_t)s0 * D))[lane];
        float2 v1 = ((const float2*)(x + (size_t)s1 * D))[lane];
        float2 v2 = ((const float2*)(x + (size_t)s2 * D))[lane];
        float2 v3 = ((const float2*)(x + (size_t)s3 * D))[lane];
        accx += v0.x + v1.x + v2.x + v3.x;
        accy += v0.y + v1.y + v2.y + v3.y;
    }
    for (; j < end; ++j) {
        int s = csr_src[j];
        float2 v = ((const float2*)(x + (size_t)s * D))[lane];
        accx += v.x; accy += v.y;
    }
    float2 o; o.x = accx; o.y = accy;
    ((float2*)(agg + (size_t)wave * D))[lane] = o;
}

// out[n][j] = epilogue( nd[n] * sum_k A[n][k]*W[k][j] + b[j] )
// epilogue: relu(.) * ns[n]  -> pre-scaled input for next layer
__global__ __launch_bounds__(256) void
k_gemm(const float* __restrict__ A, const float* __restrict__ W,
       const float* __restrict__ b, const float* __restrict__ nd,
       const float* __restrict__ ns, float* __restrict__ out) {
    __shared__ float As[64][128];  // As[r][(c + r) & 127] = A[row0+r][c]
    __shared__ float Ws[64][128];  // k-half chunk
    int tid = threadIdx.x;
    int row0 = blockIdx.x * 64;

    for (int i = tid; i < 64 * 128; i += 256) {
        int r = i >> 7, c = i & 127;
        int n = row0 + r;
        As[r][(c + r) & 127] = (n < N_NODES) ? A[(size_t)n * D + c] : 0.0f;
    }

    int r = tid >> 3;          // 0..31 (also handles r+32)
    int c4 = (tid & 7) * 4;    // column base; cols = c4 + 32*g + q
    float acc[2][16];
#pragma unroll
    for (int h = 0; h < 2; h++)
#pragma unroll
        for (int j = 0; j < 16; j++) acc[h][j] = 0.0f;

    for (int ph = 0; ph < 2; ph++) {
        __syncthreads();
        for (int i = tid; i < 64 * 128; i += 256)
            Ws[i >> 7][i & 127] = W[(size_t)(ph * 64 + (i >> 7)) * D + (i & 127)];
        __syncthreads();
#pragma unroll 4
        for (int kk = 0; kk < 64; kk++) {
            int k = ph * 64 + kk;
            float a0 = As[r][(k + r) & 127];
            float a1 = As[r + 32][(k + r + 32) & 127];
#pragma unroll
            for (int g = 0; g < 4; g++) {
                float4 w = *(const float4*)&Ws[kk][c4 + 32 * g];
                acc[0][g * 4 + 0] = fmaf(a0, w.x, acc[0][g * 4 + 0]);
                acc[0][g * 4 + 1] = fmaf(a0, w.y, acc[0][g * 4 + 1]);
                acc[0][g * 4 + 2] = fmaf(a0, w.z, acc[0][g * 4 + 2]);
                acc[0][g * 4 + 3] = fmaf(a0, w.w, acc[0][g * 4 + 3]);
                acc[1][g * 4 + 0] = fmaf(a1, w.x, acc[1][g * 4 + 0]);
                acc[1][g * 4 + 1] = fmaf(a1, w.y, acc[1][g * 4 + 1]);
                acc[1][g * 4 + 2] = fmaf(a1, w.z, acc[1][g * 4 + 2]);
                acc[1][g * 4 + 3] = fmaf(a1, w.w, acc[1][g * 4 + 3]);
            }
        }
    }

#pragma unroll
    for (int h = 0; h < 2; h++) {
        int n = row0 + r + h * 32;
        if (n >= N_NODES) continue;
        float sd = nd[n];
        float ss = ns[n];
        float* orow = out + (size_t)n * D;
#pragma unroll
        for (int g = 0; g < 4; g++) {
            float4 v;
            float bx = b[c4 + 32 * g + 0], by = b[c4 + 32 * g + 1];
            float bz = b[c4 + 32 * g + 2], bw = b[c4 + 32 * g + 3];
            v.x = fmaxf(sd * acc[h][g * 4 + 0] + bx, 0.0f) * ss;
            v.y = fmaxf(sd * acc[h][g * 4 + 1] + by, 0.0f) * ss;
            v.z = fmaxf(sd * acc[h][g * 4 + 2] + bz, 0.0f) * ss;
            v.w = fmaxf(sd * acc[h][g * 4 + 3] + bw, 0.0f) * ss;
            *(float4*)(orow + c4 + 32 * g) = v;
        }
    }
}

// colsum[c] = sum_n nd[n] * agg[n][c]
__global__ void k_colsum(const float* __restrict__ agg, const float* __restrict__ nd,
                         float* __restrict__ colsum) {
    __shared__ float part[128];
    int t = threadIdx.x;
    int c = t & 127, half = t >> 7;
    int chunk = (N_NODES + gridDim.x - 1) / gridDim.x;
    int r0 = blockIdx.x * chunk;
    int r1 = min(r0 + chunk, N_NODES);
    float acc = 0.0f;
    for (int r = r0 + half; r < r1; r += 2)
        acc += nd[r] * agg[(size_t)r * D + c];
    if (half) part[c] = acc;
    __syncthreads();
    if (!half) unsafeAtomicAdd(&colsum[c], acc + part[c]);
}

// out[j] = (colsum/N) @ W2 [:,j] + b2[j]
__global__ void k_final(const float* __restrict__ colsum, const float* __restrict__ W,
                        const float* __restrict__ b, float* __restrict__ out) {
    __shared__ float m[128];
    int j = threadIdx.x;
    m[j] = colsum[j] * (1.0f / N_NODES);
    __syncthreads();
    float acc = b[j];
    for (int k = 0; k < 128; k++)
        acc = fmaf(m[k], W[(size_t)k * D + j], acc);
    out[j] = acc;
}

extern "C" void kernel_launch(void* const* d_in, const int* in_sizes, int n_in,
                              void* d_out, int out_size, void* d_ws, size_t ws_size,
                              hipStream_t stream) {
    const float* h   = (const float*)d_in[0];
    const int*   src = (const int*)d_in[1];
    const int*   dst = (const int*)d_in[2];
    const float* W0  = (const float*)d_in[3];
    const float* b0  = (const float*)d_in[4];
    const float* W1  = (const float*)d_in[5];
    const float* b1  = (const float*)d_in[6];
    const float* W2  = (const float*)d_in[7];
    const float* b2  = (const float*)d_in[8];
    float* out = (float*)d_out;

    // persistent workspace
    float* ns      = (float*)d_ws;                       // N
    float* nd      = ns + N_NODES;                       // N
    float* colsum  = nd + N_NODES;                       // 128
    float* bufA    = colsum + 128;                       // N*D
    float* bufB    = bufA + (size_t)N_NODES * D;         // N*D
    int*   row_ptr = (int*)(bufB + (size_t)N_NODES * D); // N+1
    int*   csr_src = row_ptr + N_NODES + 1;              // E
    // temps aliased into bufA (bufA first written by k_scale_rows, after these die)
    int* cnt_src = (int*)bufA;        // N
    int* cnt_dst = cnt_src + N_NODES; // N
    int* cursor  = cnt_dst + N_NODES; // N
    int* blkSums = cursor + N_NODES;  // 128

    // ---- CSR build + norms ----
    hipMemsetAsync(cnt_src, 0, 2 * N_NODES * sizeof(int), stream);
    k_hist<<<2048, 256, 0, stream>>>(src, dst, cnt_src, cnt_dst);
    k_scan1<<<SCAN_NB, 1024, 0, stream>>>(cnt_dst, row_ptr + 1, blkSums);
    k_scan2<<<1, 128, 0, stream>>>(blkSums);
    k_scan3<<<(N_NODES + 255) / 256, 256, 0, stream>>>(cnt_dst, row_ptr, cursor, blkSums);
    k_norm2<<<(N_NODES + 255) / 256, 256, 0, stream>>>(cnt_src, cnt_dst, ns, nd);
    k_scatter<<<2048, 256, 0, stream>>>(src, dst, cursor, csr_src);

    // x0s = h * ns  (pre-scaled by norm_src)
    k_scale_rows<<<(N_NODES * (D / 4) + 255) / 256, 256, 0, stream>>>(h, ns, bufA);

    const float* Wl[3] = {W0, W1, W2};
    const float* bl[3] = {b0, b1, b2};
    for (int l = 0; l < 3; l++) {
        k_spmm_pull<<<(N_NODES + 3) / 4, 256, 0, stream>>>(bufA, row_ptr, csr_src, bufB);
        if (l < 2) {
            k_gemm<<<(N_NODES + 63) / 64, 256, 0, stream>>>(bufB, Wl[l], bl[l], nd, ns, bufA);
        } else {
            hipMemsetAsync(colsum, 0, 128 * sizeof(float), stream);
            k_colsum<<<256, 256, 0, stream>>>(bufB, nd, colsum);
            k_final<<<1, 128, 0, stream>>>(colsum, W2, b2, out);
        }
    }
}

// Round 3
// 820.379 us; speedup vs baseline: 5.4870x; 1.2223x over previous
//
#include <hip/hip_runtime.h>
#include <hip/hip_fp16.h>

#define N_NODES 100000
#define N_EDGES 1600000
#define D 128
#define SCAN_NB ((N_NODES + 1023) / 1024)   // 98
#define NSHARD 8
#define SHARD_SZ (N_NODES / NSHARD)         // 12500 exactly

// ---------------------------------------------------------------------------
// XCD-sharded histogram: block handles node range r = blockIdx&7 (maps to XCD r
// under round-robin dispatch); its atomics stay in one L2 -> no line ping-pong.
__global__ void k_hist(const int* __restrict__ src, const int* __restrict__ dst,
                       int* __restrict__ cnt_src, int* __restrict__ cnt_dst) {
    int r = blockIdx.x & 7;
    int lo = r * SHARD_SZ, hi = lo + SHARD_SZ;
    int cohort = blockIdx.x >> 3;
    int stride = (gridDim.x >> 3) * blockDim.x;
    int i = cohort * blockDim.x + threadIdx.x;
    for (; i < N_EDGES; i += stride) {
        int s = src[i];
        int d = dst[i];
        if (s >= lo && s < hi) atomicAdd(&cnt_src[s], 1);
        if (d >= lo && d < hi) atomicAdd(&cnt_dst[d], 1);
    }
}

// block-local inclusive scan of cnt (1024/block) -> rp1[i]; block totals -> blkSums
__global__ __launch_bounds__(1024) void
k_scan1(const int* __restrict__ cnt, int* __restrict__ rp1, int* __restrict__ blkSums) {
    __shared__ int s[1024];
    int tid = threadIdx.x;
    int i = blockIdx.x * 1024 + tid;
    int v = (i < N_NODES) ? cnt[i] : 0;
    s[tid] = v;
    __syncthreads();
    for (int d = 1; d < 1024; d <<= 1) {
        int t = (tid >= d) ? s[tid - d] : 0;
        __syncthreads();
        s[tid] += t;
        __syncthreads();
    }
    if (i < N_NODES) rp1[i] = s[tid];
    if (tid == 1023) blkSums[blockIdx.x] = s[1023];
}

__global__ void k_scan2(int* __restrict__ blkSums) {
    __shared__ int s[128];
    int tid = threadIdx.x;
    int v = (tid < SCAN_NB) ? blkSums[tid] : 0;
    s[tid] = v;
    __syncthreads();
    for (int d = 1; d < 128; d <<= 1) {
        int t = (tid >= d) ? s[tid - d] : 0;
        __syncthreads();
        s[tid] += t;
        __syncthreads();
    }
    if (tid < SCAN_NB) blkSums[tid] = s[tid] - v;  // exclusive
}

__global__ void k_scan3(const int* __restrict__ cnt, int* __restrict__ row_ptr,
                        int* __restrict__ cursor, const int* __restrict__ blkSums) {
    int i = blockIdx.x * blockDim.x + threadIdx.x;
    if (i >= N_NODES) return;
    int v = row_ptr[1 + i] + blkSums[i >> 10];  // global inclusive
    row_ptr[1 + i] = v;
    cursor[i] = v - cnt[i];
    if (i == 0) row_ptr[0] = 0;
}

__global__ void k_norm2(const int* __restrict__ cnt_src, const int* __restrict__ cnt_dst,
                        float* __restrict__ ns, float* __restrict__ nd) {
    int i = blockIdx.x * blockDim.x + threadIdx.x;
    if (i >= N_NODES) return;
    ns[i] = rsqrtf((float)max(cnt_src[i], 1));
    nd[i] = rsqrtf((float)max(cnt_dst[i], 1));
}

// XCD-sharded scatter: same range trick — cursor atomics + csr stores land in
// one XCD's L2 segment (~800 KB), written back once instead of thrashing.
__global__ void k_scatter(const int* __restrict__ src, const int* __restrict__ dst,
                          int* __restrict__ cursor, int* __restrict__ csr_src) {
    int r = blockIdx.x & 7;
    int lo = r * SHARD_SZ, hi = lo + SHARD_SZ;
    int cohort = blockIdx.x >> 3;
    int stride = (gridDim.x >> 3) * blockDim.x;
    int i = cohort * blockDim.x + threadIdx.x;
    for (; i < N_EDGES; i += stride) {
        int d = dst[i];
        if (d >= lo && d < hi) {
            int pos = atomicAdd(&cursor[d], 1);
            csr_src[pos] = src[i];
        }
    }
}

// out16[n][:] = x[n][:] * ns[n]   (fp32 in, fp16 out)
__global__ void k_scale_rows(const float* __restrict__ x, const float* __restrict__ ns,
                             __half* __restrict__ out) {
    int i = blockIdx.x * blockDim.x + threadIdx.x;  // over N*D/4 float4s
    if (i >= N_NODES * (D / 4)) return;
    int n = i >> 5;
    float4 v = ((const float4*)x)[i];
    float s = ns[n];
    ((__half2*)out)[2 * i]     = __floats2half2_rn(v.x * s, v.y * s);
    ((__half2*)out)[2 * i + 1] = __floats2half2_rn(v.z * s, v.w * s);
}

// pull SpMM (fp16 gather, fp32 accum, fp16 out): one wave per node,
// lane holds half2 (cols 2*lane, 2*lane+1); no atomics.
__global__ __launch_bounds__(256) void
k_spmm(const __half* __restrict__ x, const int* __restrict__ row_ptr,
       const int* __restrict__ csr_src, __half* __restrict__ agg) {
    int wave = (blockIdx.x * blockDim.x + threadIdx.x) >> 6;
    int lane = threadIdx.x & 63;
    if (wave >= N_NODES) return;
    int beg = row_ptr[wave], end = row_ptr[wave + 1];
    float accx = 0.0f, accy = 0.0f;
    int j = beg;
    for (; j + 3 < end; j += 4) {
        int s0 = csr_src[j], s1 = csr_src[j + 1];
        int s2 = csr_src[j + 2], s3 = csr_src[j + 3];
        float2 v0 = __half22float2(((const __half2*)(x + (size_t)s0 * D))[lane]);
        float2 v1 = __half22float2(((const __half2*)(x + (size_t)s1 * D))[lane]);
        float2 v2 = __half22float2(((const __half2*)(x + (size_t)s2 * D))[lane]);
        float2 v3 = __half22float2(((const __half2*)(x + (size_t)s3 * D))[lane]);
        accx += v0.x + v1.x + v2.x + v3.x;
        accy += v0.y + v1.y + v2.y + v3.y;
    }
    for (; j < end; ++j) {
        int s = csr_src[j];
        float2 v = __half22float2(((const __half2*)(x + (size_t)s * D))[lane]);
        accx += v.x; accy += v.y;
    }
    ((__half2*)(agg + (size_t)wave * D))[lane] = __floats2half2_rn(accx, accy);
}

// out16[n][j] = relu( nd[n] * sum_k A16[n][k]*W[k][j] + b[j] ) * ns[n]
// A fp16 in, compute fp32, fp16 out. 64x128 tile, 256 thr, 2x16 reg blocking.
__global__ __launch_bounds__(256) void
k_gemm(const __half* __restrict__ A, const float* __restrict__ W,
       const float* __restrict__ b, const float* __restrict__ nd,
       const float* __restrict__ ns, __half* __restrict__ out) {
    __shared__ float As[64][128];  // As[r][(c + r) & 127] = A[row0+r][c]
    __shared__ float Ws[64][128];  // k-half chunk
    int tid = threadIdx.x;
    int row0 = blockIdx.x * 64;

    for (int i = tid; i < 64 * 64; i += 256) {  // half2 units
        int r = i >> 6, c2 = i & 63;
        int n = row0 + r;
        float2 f = make_float2(0.0f, 0.0f);
        if (n < N_NODES)
            f = __half22float2(((const __half2*)(A + (size_t)n * D))[c2]);
        int c = 2 * c2;
        As[r][(c + r) & 127] = f.x;
        As[r][(c + 1 + r) & 127] = f.y;
    }

    int r = tid >> 3;          // 0..31 (also handles r+32)
    int c4 = (tid & 7) * 4;    // column base; cols = c4 + 32*g + q
    float acc[2][16];
#pragma unroll
    for (int h = 0; h < 2; h++)
#pragma unroll
        for (int j = 0; j < 16; j++) acc[h][j] = 0.0f;

    for (int ph = 0; ph < 2; ph++) {
        __syncthreads();
        for (int i = tid; i < 64 * 128; i += 256)
            Ws[i >> 7][i & 127] = W[(size_t)(ph * 64 + (i >> 7)) * D + (i & 127)];
        __syncthreads();
#pragma unroll 4
        for (int kk = 0; kk < 64; kk++) {
            int k = ph * 64 + kk;
            float a0 = As[r][(k + r) & 127];
            float a1 = As[r + 32][(k + r + 32) & 127];
#pragma unroll
            for (int g = 0; g < 4; g++) {
                float4 w = *(const float4*)&Ws[kk][c4 + 32 * g];
                acc[0][g * 4 + 0] = fmaf(a0, w.x, acc[0][g * 4 + 0]);
                acc[0][g * 4 + 1] = fmaf(a0, w.y, acc[0][g * 4 + 1]);
                acc[0][g * 4 + 2] = fmaf(a0, w.z, acc[0][g * 4 + 2]);
                acc[0][g * 4 + 3] = fmaf(a0, w.w, acc[0][g * 4 + 3]);
                acc[1][g * 4 + 0] = fmaf(a1, w.x, acc[1][g * 4 + 0]);
                acc[1][g * 4 + 1] = fmaf(a1, w.y, acc[1][g * 4 + 1]);
                acc[1][g * 4 + 2] = fmaf(a1, w.z, acc[1][g * 4 + 2]);
                acc[1][g * 4 + 3] = fmaf(a1, w.w, acc[1][g * 4 + 3]);
            }
        }
    }

#pragma unroll
    for (int h = 0; h < 2; h++) {
        int n = row0 + r + h * 32;
        if (n >= N_NODES) continue;
        float sd = nd[n];
        float ss = ns[n];
        __half* orow = out + (size_t)n * D;
#pragma unroll
        for (int g = 0; g < 4; g++) {
            int col = c4 + 32 * g;
            float vx = fmaxf(sd * acc[h][g * 4 + 0] + b[col + 0], 0.0f) * ss;
            float vy = fmaxf(sd * acc[h][g * 4 + 1] + b[col + 1], 0.0f) * ss;
            float vz = fmaxf(sd * acc[h][g * 4 + 2] + b[col + 2], 0.0f) * ss;
            float vw = fmaxf(sd * acc[h][g * 4 + 3] + b[col + 3], 0.0f) * ss;
            *(__half2*)(orow + col)     = __floats2half2_rn(vx, vy);
            *(__half2*)(orow + col + 2) = __floats2half2_rn(vz, vw);
        }
    }
}

// colsum[c] = sum_n nd[n] * agg16[n][c]
__global__ void k_colsum(const __half* __restrict__ agg, const float* __restrict__ nd,
                         float* __restrict__ colsum) {
    __shared__ float part[128];
    int t = threadIdx.x;
    int c = t & 127, half = t >> 7;
    int chunk = (N_NODES + gridDim.x - 1) / gridDim.x;
    int r0 = blockIdx.x * chunk;
    int r1 = min(r0 + chunk, N_NODES);
    float acc = 0.0f;
    for (int r = r0 + half; r < r1; r += 2)
        acc += nd[r] * __half2float(agg[(size_t)r * D + c]);
    if (half) part[c] = acc;
    __syncthreads();
    if (!half) unsafeAtomicAdd(&colsum[c], acc + part[c]);
}

// out[j] = (colsum/N) @ W2 [:,j] + b2[j]
__global__ void k_final(const float* __restrict__ colsum, const float* __restrict__ W,
                        const float* __restrict__ b, float* __restrict__ out) {
    __shared__ float m[128];
    int j = threadIdx.x;
    m[j] = colsum[j] * (1.0f / N_NODES);
    __syncthreads();
    float acc = b[j];
    for (int k = 0; k < 128; k++)
        acc = fmaf(m[k], W[(size_t)k * D + j], acc);
    out[j] = acc;
}

extern "C" void kernel_launch(void* const* d_in, const int* in_sizes, int n_in,
                              void* d_out, int out_size, void* d_ws, size_t ws_size,
                              hipStream_t stream) {
    const float* h   = (const float*)d_in[0];
    const int*   src = (const int*)d_in[1];
    const int*   dst = (const int*)d_in[2];
    const float* W0  = (const float*)d_in[3];
    const float* b0  = (const float*)d_in[4];
    const float* W1  = (const float*)d_in[5];
    const float* b1  = (const float*)d_in[6];
    const float* W2  = (const float*)d_in[7];
    const float* b2  = (const float*)d_in[8];
    float* out = (float*)d_out;

    // workspace layout (~62 MB; ws previously held >100 MB)
    float*  ns      = (float*)d_ws;                        // N
    float*  nd      = ns + N_NODES;                        // N
    float*  colsum  = nd + N_NODES;                        // 128
    int*    row_ptr = (int*)(colsum + 128);                // N+1
    int*    csr_src = row_ptr + N_NODES + 1;               // E
    __half* x16     = (__half*)(csr_src + N_EDGES);        // N*D halves
    __half* agg16   = x16 + (size_t)N_NODES * D;           // N*D halves
    int*    cnt_src = (int*)(agg16 + (size_t)N_NODES * D); // N
    int*    cnt_dst = cnt_src + N_NODES;                   // N
    int*    cursor  = cnt_dst + N_NODES;                   // N
    int*    blkSums = cursor + N_NODES;                    // 128

    // ---- CSR build + norms ----
    hipMemsetAsync(cnt_src, 0, 2 * N_NODES * sizeof(int), stream);
    k_hist<<<2048, 256, 0, stream>>>(src, dst, cnt_src, cnt_dst);
    k_scan1<<<SCAN_NB, 1024, 0, stream>>>(cnt_dst, row_ptr + 1, blkSums);
    k_scan2<<<1, 128, 0, stream>>>(blkSums);
    k_scan3<<<(N_NODES + 255) / 256, 256, 0, stream>>>(cnt_dst, row_ptr, cursor, blkSums);
    k_norm2<<<(N_NODES + 255) / 256, 256, 0, stream>>>(cnt_src, cnt_dst, ns, nd);
    k_scatter<<<2048, 256, 0, stream>>>(src, dst, cursor, csr_src);

    // x0s = h * ns  (pre-scaled by norm_src, fp16)
    k_scale_rows<<<(N_NODES * (D / 4) + 255) / 256, 256, 0, stream>>>(h, ns, x16);

    const float* Wl[3] = {W0, W1, W2};
    const float* bl[3] = {b0, b1, b2};
    for (int l = 0; l < 3; l++) {
        k_spmm<<<(N_NODES + 3) / 4, 256, 0, stream>>>(x16, row_ptr, csr_src, agg16);
        if (l < 2) {
            k_gemm<<<(N_NODES + 63) / 64, 256, 0, stream>>>(agg16, Wl[l], bl[l], nd, ns, x16);
        } else {
            hipMemsetAsync(colsum, 0, 128 * sizeof(float), stream);
            k_colsum<<<256, 256, 0, stream>>>(agg16, nd, colsum);
            k_final<<<1, 128, 0, stream>>>(colsum, W2, b2, out);
        }
    }
}

// Round 4
// 804.809 us; speedup vs baseline: 5.5931x; 1.0193x over previous
//
#include <hip/hip_runtime.h>
#include <hip/hip_fp16.h>

#define N_NODES 100000
#define N_EDGES 1600000
#define D 128
#define SCAN_NB ((N_NODES + 1023) / 1024)   // 98
#define NSHARD 8
#define SH (N_NODES / NSHARD)               // 12500 nodes per shard
#define CHK 32                              // edge chunks
#define CHUNK_E (N_EDGES / CHK)             // 50000 edges per chunk

// ---------------------------------------------------------------------------
// Pass A: LDS-privatized partial histograms. job = arr*8 + shard (arr 0=src,
// 1=dst), chunk c. NO global atomics (global atomics write ~32B through to
// fabric per op — measured 97MB WRITE_SIZE for 800KB of counters in R3).
__global__ __launch_bounds__(256) void
k_hist_part(const int* __restrict__ src, const int* __restrict__ dst,
            int* __restrict__ partials) {
    __shared__ int hcnt[SH];  // 50 KB
    int job = blockIdx.x / CHK;   // 0..15
    int c   = blockIdx.x % CHK;
    const int* arr = (job < 8) ? src : dst;
    int lo = (job & 7) * SH;
    for (int i = threadIdx.x; i < SH; i += 256) hcnt[i] = 0;
    __syncthreads();
    int e0 = c * CHUNK_E;
    for (int i = e0 + threadIdx.x; i < e0 + CHUNK_E; i += 256) {
        int v = arr[i] - lo;
        if ((unsigned)v < SH) atomicAdd(&hcnt[v], 1);
    }
    __syncthreads();
    int* p = partials + ((size_t)job * CHK + c) * SH;
    for (int i = threadIdx.x; i < SH; i += 256) p[i] = hcnt[i];
}

// Pass B: cnt[j][i] = sum_c partial[j][c][i]; dst jobs also converted in-place
// to exclusive prefix over c (per-chunk base offsets for the scatter).
__global__ void k_hist_merge(int* __restrict__ partials, int* __restrict__ cnt_src,
                             int* __restrict__ cnt_dst) {
    int g = blockIdx.x * blockDim.x + threadIdx.x;  // over 16*SH
    if (g >= 16 * SH) return;
    int job = g / SH, i = g % SH;
    int* p = partials + ((size_t)job * CHK) * SH + i;
    int sum = 0;
    if (job < 8) {
#pragma unroll 8
        for (int c = 0; c < CHK; c++) sum += p[(size_t)c * SH];
        cnt_src[(job & 7) * SH + i] = sum;
    } else {
#pragma unroll 8
        for (int c = 0; c < CHK; c++) {
            int v = p[(size_t)c * SH];
            p[(size_t)c * SH] = sum;
            sum += v;
        }
        cnt_dst[(job & 7) * SH + i] = sum;
    }
}

// block-local inclusive scan of cnt (1024/block) -> rp1[i]; block totals -> blkSums
__global__ __launch_bounds__(1024) void
k_scan1(const int* __restrict__ cnt, int* __restrict__ rp1, int* __restrict__ blkSums) {
    __shared__ int s[1024];
    int tid = threadIdx.x;
    int i = blockIdx.x * 1024 + tid;
    int v = (i < N_NODES) ? cnt[i] : 0;
    s[tid] = v;
    __syncthreads();
    for (int d = 1; d < 1024; d <<= 1) {
        int t = (tid >= d) ? s[tid - d] : 0;
        __syncthreads();
        s[tid] += t;
        __syncthreads();
    }
    if (i < N_NODES) rp1[i] = s[tid];
    if (tid == 1023) blkSums[blockIdx.x] = s[1023];
}

__global__ void k_scan2(int* __restrict__ blkSums) {
    __shared__ int s[128];
    int tid = threadIdx.x;
    int v = (tid < SCAN_NB) ? blkSums[tid] : 0;
    s[tid] = v;
    __syncthreads();
    for (int d = 1; d < 128; d <<= 1) {
        int t = (tid >= d) ? s[tid - d] : 0;
        __syncthreads();
        s[tid] += t;
        __syncthreads();
    }
    if (tid < SCAN_NB) blkSums[tid] = s[tid] - v;  // exclusive
}

__global__ void k_scan3(int* __restrict__ row_ptr, const int* __restrict__ blkSums) {
    int i = blockIdx.x * blockDim.x + threadIdx.x;
    if (i >= N_NODES) return;
    row_ptr[1 + i] += blkSums[i >> 10];  // global inclusive
    if (i == 0) row_ptr[0] = 0;
}

__global__ void k_norm2(const int* __restrict__ cnt_src, const int* __restrict__ cnt_dst,
                        float* __restrict__ ns, float* __restrict__ nd) {
    int i = blockIdx.x * blockDim.x + threadIdx.x;
    if (i >= N_NODES) return;
    ns[i] = rsqrtf((float)max(cnt_src[i], 1));
    nd[i] = rsqrtf((float)max(cnt_dst[i], 1));
}

// Pass C: counting-sort scatter. Block (shard s = blockIdx&7 for XCD affinity,
// chunk c) seeds LDS cursors = row_ptr + per-chunk prefix, then places edges
// using LDS atomics only; csr stores are plain write-back stores, disjoint
// across blocks.
__global__ __launch_bounds__(256) void
k_scatter2(const int* __restrict__ src, const int* __restrict__ dst,
           const int* __restrict__ row_ptr, const int* __restrict__ partials,
           int* __restrict__ csr_src) {
    __shared__ int cur[SH];  // 50 KB
    int s = blockIdx.x & 7;
    int c = blockIdx.x >> 3;
    int lo = s * SH;
    const int* pre = partials + ((size_t)(8 + s) * CHK + c) * SH;
    for (int i = threadIdx.x; i < SH; i += 256)
        cur[i] = row_ptr[lo + i] + pre[i];
    __syncthreads();
    int e0 = c * CHUNK_E;
    for (int i = e0 + threadIdx.x; i < e0 + CHUNK_E; i += 256) {
        int d = dst[i] - lo;
        if ((unsigned)d < SH) {
            int pos = atomicAdd(&cur[d], 1);
            csr_src[pos] = src[i];
        }
    }
}

// out16[n][:] = x[n][:] * ns[n]   (fp32 in, fp16 out)
__global__ void k_scale_rows(const float* __restrict__ x, const float* __restrict__ ns,
                             __half* __restrict__ out) {
    int i = blockIdx.x * blockDim.x + threadIdx.x;  // over N*D/4 float4s
    if (i >= N_NODES * (D / 4)) return;
    int n = i >> 5;
    float4 v = ((const float4*)x)[i];
    float s = ns[n];
    ((__half2*)out)[2 * i]     = __floats2half2_rn(v.x * s, v.y * s);
    ((__half2*)out)[2 * i + 1] = __floats2half2_rn(v.z * s, v.w * s);
}

// pull SpMM (fp16 gather, fp32 accum, fp16 out): one wave per node,
// lane holds half2 (cols 2*lane, 2*lane+1); no atomics.
__global__ __launch_bounds__(256) void
k_spmm(const __half* __restrict__ x, const int* __restrict__ row_ptr,
       const int* __restrict__ csr_src, __half* __restrict__ agg) {
    int wave = (blockIdx.x * blockDim.x + threadIdx.x) >> 6;
    int lane = threadIdx.x & 63;
    if (wave >= N_NODES) return;
    int beg = row_ptr[wave], end = row_ptr[wave + 1];
    float accx = 0.0f, accy = 0.0f;
    int j = beg;
    for (; j + 3 < end; j += 4) {
        int s0 = csr_src[j], s1 = csr_src[j + 1];
        int s2 = csr_src[j + 2], s3 = csr_src[j + 3];
        float2 v0 = __half22float2(((const __half2*)(x + (size_t)s0 * D))[lane]);
        float2 v1 = __half22float2(((const __half2*)(x + (size_t)s1 * D))[lane]);
        float2 v2 = __half22float2(((const __half2*)(x + (size_t)s2 * D))[lane]);
        float2 v3 = __half22float2(((const __half2*)(x + (size_t)s3 * D))[lane]);
        accx += v0.x + v1.x + v2.x + v3.x;
        accy += v0.y + v1.y + v2.y + v3.y;
    }
    for (; j < end; ++j) {
        int s = csr_src[j];
        float2 v = __half22float2(((const __half2*)(x + (size_t)s * D))[lane]);
        accx += v.x; accy += v.y;
    }
    ((__half2*)(agg + (size_t)wave * D))[lane] = __floats2half2_rn(accx, accy);
}

// out16[n][j] = relu( nd[n] * sum_k A16[n][k]*W[k][j] + b[j] ) * ns[n]
__global__ __launch_bounds__(256) void
k_gemm(const __half* __restrict__ A, const float* __restrict__ W,
       const float* __restrict__ b, const float* __restrict__ nd,
       const float* __restrict__ ns, __half* __restrict__ out) {
    __shared__ float As[64][128];  // As[r][(c + r) & 127] = A[row0+r][c]
    __shared__ float Ws[64][128];  // k-half chunk
    int tid = threadIdx.x;
    int row0 = blockIdx.x * 64;

    for (int i = tid; i < 64 * 64; i += 256) {  // half2 units
        int r = i >> 6, c2 = i & 63;
        int n = row0 + r;
        float2 f = make_float2(0.0f, 0.0f);
        if (n < N_NODES)
            f = __half22float2(((const __half2*)(A + (size_t)n * D))[c2]);
        int c = 2 * c2;
        As[r][(c + r) & 127] = f.x;
        As[r][(c + 1 + r) & 127] = f.y;
    }

    int r = tid >> 3;
    int c4 = (tid & 7) * 4;
    float acc[2][16];
#pragma unroll
    for (int h = 0; h < 2; h++)
#pragma unroll
        for (int j = 0; j < 16; j++) acc[h][j] = 0.0f;

    for (int ph = 0; ph < 2; ph++) {
        __syncthreads();
        for (int i = tid; i < 64 * 128; i += 256)
            Ws[i >> 7][i & 127] = W[(size_t)(ph * 64 + (i >> 7)) * D + (i & 127)];
        __syncthreads();
#pragma unroll 4
        for (int kk = 0; kk < 64; kk++) {
            int k = ph * 64 + kk;
            float a0 = As[r][(k + r) & 127];
            float a1 = As[r + 32][(k + r + 32) & 127];
#pragma unroll
            for (int g = 0; g < 4; g++) {
                float4 w = *(const float4*)&Ws[kk][c4 + 32 * g];
                acc[0][g * 4 + 0] = fmaf(a0, w.x, acc[0][g * 4 + 0]);
                acc[0][g * 4 + 1] = fmaf(a0, w.y, acc[0][g * 4 + 1]);
                acc[0][g * 4 + 2] = fmaf(a0, w.z, acc[0][g * 4 + 2]);
                acc[0][g * 4 + 3] = fmaf(a0, w.w, acc[0][g * 4 + 3]);
                acc[1][g * 4 + 0] = fmaf(a1, w.x, acc[1][g * 4 + 0]);
                acc[1][g * 4 + 1] = fmaf(a1, w.y, acc[1][g * 4 + 1]);
                acc[1][g * 4 + 2] = fmaf(a1, w.z, acc[1][g * 4 + 2]);
                acc[1][g * 4 + 3] = fmaf(a1, w.w, acc[1][g * 4 + 3]);
            }
        }
    }

#pragma unroll
    for (int h = 0; h < 2; h++) {
        int n = row0 + r + h * 32;
        if (n >= N_NODES) continue;
        float sd = nd[n];
        float ss = ns[n];
        __half* orow = out + (size_t)n * D;
#pragma unroll
        for (int g = 0; g < 4; g++) {
            int col = c4 + 32 * g;
            float vx = fmaxf(sd * acc[h][g * 4 + 0] + b[col + 0], 0.0f) * ss;
            float vy = fmaxf(sd * acc[h][g * 4 + 1] + b[col + 1], 0.0f) * ss;
            float vz = fmaxf(sd * acc[h][g * 4 + 2] + b[col + 2], 0.0f) * ss;
            float vw = fmaxf(sd * acc[h][g * 4 + 3] + b[col + 3], 0.0f) * ss;
            *(__half2*)(orow + col)     = __floats2half2_rn(vx, vy);
            *(__half2*)(orow + col + 2) = __floats2half2_rn(vz, vw);
        }
    }
}

// colsum[c] = sum_n nd[n] * agg16[n][c]
__global__ void k_colsum(const __half* __restrict__ agg, const float* __restrict__ nd,
                         float* __restrict__ colsum) {
    __shared__ float part[128];
    int t = threadIdx.x;
    int c = t & 127, half = t >> 7;
    int chunk = (N_NODES + gridDim.x - 1) / gridDim.x;
    int r0 = blockIdx.x * chunk;
    int r1 = min(r0 + chunk, N_NODES);
    float acc = 0.0f;
    for (int r = r0 + half; r < r1; r += 2)
        acc += nd[r] * __half2float(agg[(size_t)r * D + c]);
    if (half) part[c] = acc;
    __syncthreads();
    if (!half) unsafeAtomicAdd(&colsum[c], acc + part[c]);
}

// out[j] = (colsum/N) @ W2 [:,j] + b2[j]
__global__ void k_final(const float* __restrict__ colsum, const float* __restrict__ W,
                        const float* __restrict__ b, float* __restrict__ out) {
    __shared__ float m[128];
    int j = threadIdx.x;
    m[j] = colsum[j] * (1.0f / N_NODES);
    __syncthreads();
    float acc = b[j];
    for (int k = 0; k < 128; k++)
        acc = fmaf(m[k], W[(size_t)k * D + j], acc);
    out[j] = acc;
}

extern "C" void kernel_launch(void* const* d_in, const int* in_sizes, int n_in,
                              void* d_out, int out_size, void* d_ws, size_t ws_size,
                              hipStream_t stream) {
    const float* h   = (const float*)d_in[0];
    const int*   src = (const int*)d_in[1];
    const int*   dst = (const int*)d_in[2];
    const float* W0  = (const float*)d_in[3];
    const float* b0  = (const float*)d_in[4];
    const float* W1  = (const float*)d_in[5];
    const float* b1  = (const float*)d_in[6];
    const float* W2  = (const float*)d_in[7];
    const float* b2  = (const float*)d_in[8];
    float* out = (float*)d_out;

    // workspace layout (~86 MB)
    float*  ns       = (float*)d_ws;                        // N
    float*  nd       = ns + N_NODES;                        // N
    float*  colsum   = nd + N_NODES;                        // 128
    int*    row_ptr  = (int*)(colsum + 128);                // N+1
    int*    cnt_src  = row_ptr + N_NODES + 1;               // N
    int*    cnt_dst  = cnt_src + N_NODES;                   // N
    int*    blkSums  = cnt_dst + N_NODES;                   // 128
    int*    csr_src  = blkSums + 128;                       // E
    int*    partials = csr_src + N_EDGES;                   // 16*CHK*SH = 6.4M ints
    __half* x16      = (__half*)(partials + 16 * CHK * SH); // N*D halves
    __half* agg16    = x16 + (size_t)N_NODES * D;           // N*D halves

    // ---- CSR build + norms (no global atomics) ----
    k_hist_part<<<16 * CHK, 256, 0, stream>>>(src, dst, partials);
    k_hist_merge<<<(16 * SH + 255) / 256, 256, 0, stream>>>(partials, cnt_src, cnt_dst);
    k_scan1<<<SCAN_NB, 1024, 0, stream>>>(cnt_dst, row_ptr + 1, blkSums);
    k_scan2<<<1, 128, 0, stream>>>(blkSums);
    k_scan3<<<(N_NODES + 255) / 256, 256, 0, stream>>>(row_ptr, blkSums);
    k_norm2<<<(N_NODES + 255) / 256, 256, 0, stream>>>(cnt_src, cnt_dst, ns, nd);
    k_scatter2<<<NSHARD * CHK, 256, 0, stream>>>(src, dst, row_ptr, partials, csr_src);

    // x0s = h * ns  (pre-scaled by norm_src, fp16)
    k_scale_rows<<<(N_NODES * (D / 4) + 255) / 256, 256, 0, stream>>>(h, ns, x16);

    const float* Wl[3] = {W0, W1, W2};
    const float* bl[3] = {b0, b1, b2};
    for (int l = 0; l < 3; l++) {
        k_spmm<<<(N_NODES + 3) / 4, 256, 0, stream>>>(x16, row_ptr, csr_src, agg16);
        if (l < 2) {
            k_gemm<<<(N_NODES + 63) / 64, 256, 0, stream>>>(agg16, Wl[l], bl[l], nd, ns, x16);
        } else {
            hipMemsetAsync(colsum, 0, 128 * sizeof(float), stream);
            k_colsum<<<256, 256, 0, stream>>>(agg16, nd, colsum);
            k_final<<<1, 128, 0, stream>>>(colsum, W2, b2, out);
        }
    }
}

// Round 5
// 603.725 us; speedup vs baseline: 7.4561x; 1.3331x over previous
//
#include <hip/hip_runtime.h>
#include <hip/hip_fp16.h>

#define N_NODES 100000
#define N_EDGES 1600000
#define D 128
#define SCAN_NB ((N_NODES + 1023) / 1024)   // 98
#define NSHARD 8
#define SH (N_NODES / NSHARD)               // 12500 nodes / scatter shard
#define SH_U (SH / 2)                       // 6250 packed uints
#define CHK 64                              // edge chunks
#define CHUNK_E (N_EDGES / CHK)             // 25000 edges per chunk (<65536 -> 16-bit safe)
#define PAIR_N 25000                        // nodes per hist job (4 jobs cover N)
#define PAIR_U (PAIR_N / 2)                 // 12500 uints = 50 KB LDS
#define PPART_STRIDE (N_NODES / 2)          // 50000 packed uints per (arr,chunk)

typedef _Float16 f16x8 __attribute__((ext_vector_type(8)));
typedef float f32x4 __attribute__((ext_vector_type(4)));

// ---------------------------------------------------------------------------
// Pass A: LDS-privatized partial histograms, 16-bit packed (2 nodes per uint).
// job = arr*4 + p (arr 0=src,1=dst; p = node-quarter), chunk c. No global atomics.
__global__ __launch_bounds__(256) void
k_hist_part(const int* __restrict__ src, const int* __restrict__ dst,
            unsigned int* __restrict__ ppart) {
    __shared__ unsigned int hcnt[PAIR_U];  // 50 KB
    int jb = blockIdx.x >> 6;      // 0..7
    int c  = blockIdx.x & (CHK - 1);
    const int* arr = (jb >> 2) ? dst : src;
    int p  = jb & 3;
    int lo = p * PAIR_N;
    for (int i = threadIdx.x; i < PAIR_U; i += 256) hcnt[i] = 0;
    __syncthreads();
    int e0 = c * CHUNK_E;
    for (int i = e0 + threadIdx.x; i < e0 + CHUNK_E; i += 256) {
        int v = arr[i] - lo;
        if ((unsigned)v < PAIR_N)
            atomicAdd(&hcnt[v >> 1], 1u << ((v & 1) << 4));
    }
    __syncthreads();
    unsigned int* po = ppart + ((size_t)(jb >> 2) * CHK + c) * PPART_STRIDE + p * PAIR_U;
    for (int i = threadIdx.x; i < PAIR_U; i += 256) po[i] = hcnt[i];
}

// Pass B: unpack+sum partials -> cnt; dst partials converted in place to
// exclusive per-chunk prefix (16-bit packed, prefix <= degree << 2^16).
__global__ void k_hist_merge(unsigned int* __restrict__ ppart,
                             int* __restrict__ cnt_src, int* __restrict__ cnt_dst) {
    int g = blockIdx.x * blockDim.x + threadIdx.x;  // over 2*PPART_STRIDE
    if (g >= 2 * PPART_STRIDE) return;
    int arr = g / PPART_STRIDE, i = g % PPART_STRIDE;
    unsigned int* p = ppart + (size_t)arr * CHK * PPART_STRIDE + i;
    if (arr == 0) {
        int lo = 0, hi = 0;
#pragma unroll 8
        for (int c = 0; c < CHK; c++) {
            unsigned int u = p[(size_t)c * PPART_STRIDE];
            lo += u & 0xffff; hi += u >> 16;
        }
        cnt_src[2 * i] = lo; cnt_src[2 * i + 1] = hi;
    } else {
        int lo = 0, hi = 0;
#pragma unroll 8
        for (int c = 0; c < CHK; c++) {
            unsigned int u = p[(size_t)c * PPART_STRIDE];
            p[(size_t)c * PPART_STRIDE] = (unsigned)lo | ((unsigned)hi << 16);
            lo += u & 0xffff; hi += u >> 16;
        }
        cnt_dst[2 * i] = lo; cnt_dst[2 * i + 1] = hi;
    }
}

// block-local inclusive scan of cnt (1024/block) -> rp1[i]; block totals -> blkSums
__global__ __launch_bounds__(1024) void
k_scan1(const int* __restrict__ cnt, int* __restrict__ rp1, int* __restrict__ blkSums) {
    __shared__ int s[1024];
    int tid = threadIdx.x;
    int i = blockIdx.x * 1024 + tid;
    int v = (i < N_NODES) ? cnt[i] : 0;
    s[tid] = v;
    __syncthreads();
    for (int d = 1; d < 1024; d <<= 1) {
        int t = (tid >= d) ? s[tid - d] : 0;
        __syncthreads();
        s[tid] += t;
        __syncthreads();
    }
    if (i < N_NODES) rp1[i] = s[tid];
    if (tid == 1023) blkSums[blockIdx.x] = s[1023];
}

__global__ void k_scan2(int* __restrict__ blkSums) {
    __shared__ int s[128];
    int tid = threadIdx.x;
    int v = (tid < SCAN_NB) ? blkSums[tid] : 0;
    s[tid] = v;
    __syncthreads();
    for (int d = 1; d < 128; d <<= 1) {
        int t = (tid >= d) ? s[tid - d] : 0;
        __syncthreads();
        s[tid] += t;
        __syncthreads();
    }
    if (tid < SCAN_NB) blkSums[tid] = s[tid] - v;  // exclusive
}

__global__ void k_scan3(int* __restrict__ row_ptr, const int* __restrict__ blkSums) {
    int i = blockIdx.x * blockDim.x + threadIdx.x;
    if (i >= N_NODES) return;
    row_ptr[1 + i] += blkSums[i >> 10];
    if (i == 0) row_ptr[0] = 0;
}

__global__ void k_norm2(const int* __restrict__ cnt_src, const int* __restrict__ cnt_dst,
                        float* __restrict__ ns, float* __restrict__ nd) {
    int i = blockIdx.x * blockDim.x + threadIdx.x;
    if (i >= N_NODES) return;
    ns[i] = rsqrtf((float)max(cnt_src[i], 1));
    nd[i] = rsqrtf((float)max(cnt_dst[i], 1));
}

// Pass C: counting-sort scatter. Block (shard s = blockIdx&7 -> XCD affinity,
// chunk c). LDS cursors seeded from row_ptr + packed per-chunk prefix; LDS
// atomics only; csr stores plain, disjoint, shard-local (stays in one L2).
__global__ __launch_bounds__(256) void
k_scatter2(const int* __restrict__ src, const int* __restrict__ dst,
           const int* __restrict__ row_ptr, const unsigned int* __restrict__ ppart,
           int* __restrict__ csr_src) {
    __shared__ int cur[SH];  // 50 KB
    int s = blockIdx.x & 7;
    int c = blockIdx.x >> 3;
    int lo = s * SH;
    const unsigned int* pre = ppart + ((size_t)CHK + c) * PPART_STRIDE + s * SH_U;
    for (int t = threadIdx.x; t < SH_U; t += 256) {
        unsigned int u = pre[t];
        cur[2 * t]     = row_ptr[lo + 2 * t]     + (int)(u & 0xffff);
        cur[2 * t + 1] = row_ptr[lo + 2 * t + 1] + (int)(u >> 16);
    }
    __syncthreads();
    int e0 = c * CHUNK_E;
    for (int i = e0 + threadIdx.x; i < e0 + CHUNK_E; i += 256) {
        int d = dst[i] - lo;
        if ((unsigned)d < SH) {
            int pos = atomicAdd(&cur[d], 1);
            csr_src[pos] = src[i];
        }
    }
}

// Wt16[l][n][k] = (half) Wl[k][n]   for l = 0,1
__global__ void k_prep_w(const float* __restrict__ W0, const float* __restrict__ W1,
                         __half* __restrict__ Wt) {
    int i = blockIdx.x * blockDim.x + threadIdx.x;
    if (i >= 2 * D * D) return;
    int l = i >> 14, r = i & (D * D - 1);
    int n = r >> 7, k = r & 127;
    const float* W = l ? W1 : W0;
    Wt[i] = __float2half(W[k * D + n]);
}

// out16[n][:] = x[n][:] * ns[n]   (fp32 in, fp16 out)
__global__ void k_scale_rows(const float* __restrict__ x, const float* __restrict__ ns,
                             __half* __restrict__ out) {
    int i = blockIdx.x * blockDim.x + threadIdx.x;
    if (i >= N_NODES * (D / 4)) return;
    int n = i >> 5;
    float4 v = ((const float4*)x)[i];
    float s = ns[n];
    ((__half2*)out)[2 * i]     = __floats2half2_rn(v.x * s, v.y * s);
    ((__half2*)out)[2 * i + 1] = __floats2half2_rn(v.z * s, v.w * s);
}

// pull SpMM (fp16 gather, fp32 accum, fp16 out): one wave per node.
__global__ __launch_bounds__(256) void
k_spmm(const __half* __restrict__ x, const int* __restrict__ row_ptr,
       const int* __restrict__ csr_src, __half* __restrict__ agg) {
    int wave = (blockIdx.x * blockDim.x + threadIdx.x) >> 6;
    int lane = threadIdx.x & 63;
    if (wave >= N_NODES) return;
    int beg = row_ptr[wave], end = row_ptr[wave + 1];
    float accx = 0.0f, accy = 0.0f;
    int j = beg;
    for (; j + 3 < end; j += 4) {
        int s0 = csr_src[j], s1 = csr_src[j + 1];
        int s2 = csr_src[j + 2], s3 = csr_src[j + 3];
        float2 v0 = __half22float2(((const __half2*)(x + (size_t)s0 * D))[lane]);
        float2 v1 = __half22float2(((const __half2*)(x + (size_t)s1 * D))[lane]);
        float2 v2 = __half22float2(((const __half2*)(x + (size_t)s2 * D))[lane]);
        float2 v3 = __half22float2(((const __half2*)(x + (size_t)s3 * D))[lane]);
        accx += v0.x + v1.x + v2.x + v3.x;
        accy += v0.y + v1.y + v2.y + v3.y;
    }
    for (; j < end; ++j) {
        int s = csr_src[j];
        float2 v = __half22float2(((const __half2*)(x + (size_t)s * D))[lane]);
        accx += v.x; accy += v.y;
    }
    ((__half2*)(agg + (size_t)wave * D))[lane] = __floats2half2_rn(accx, accy);
}

// MFMA GEMM: out16[n][j] = relu( nd[n]*(A16 @ W)[n][j] + b[j] ) * ns[n]
// Per wave: 16 rows x 128 cols, K=128 in 4 steps of 32 (mfma_f32_16x16x32_f16).
// A frag: A[m=lane&15][k=quad*8+j]; B frag: Wt[n=lane&15][k=quad*8+j] (Wt=W^T);
// D: col=lane&15, row=quad*4+reg.
__global__ __launch_bounds__(256) void
k_gemm_mfma(const __half* __restrict__ A, const __half* __restrict__ Wt,
            const float* __restrict__ b, const float* __restrict__ nd,
            const float* __restrict__ ns, __half* __restrict__ out) {
    int w = threadIdx.x >> 6, lane = threadIdx.x & 63;
    int m = lane & 15, q = lane >> 4;
    int row0 = blockIdx.x * 64 + w * 16;

    // A fragments for all 4 k-steps (row guard -> zero)
    int arow = row0 + m;
    f16x8 zf;
#pragma unroll
    for (int j = 0; j < 8; j++) zf[j] = (_Float16)0;
    f16x8 af[4];
    const f16x8* pa = (const f16x8*)(A + (size_t)arow * D);
    bool aok = arow < N_NODES;
#pragma unroll
    for (int ks = 0; ks < 4; ks++) af[ks] = aok ? pa[ks * 4 + q] : zf;

    const f16x8* pb = (const f16x8*)Wt;
    f32x4 acc[8];
#pragma unroll
    for (int nt = 0; nt < 8; nt++) acc[nt] = (f32x4){0.f, 0.f, 0.f, 0.f};

#pragma unroll
    for (int ks = 0; ks < 4; ks++) {
        f16x8 bf[8];
#pragma unroll
        for (int nt = 0; nt < 8; nt++)
            bf[nt] = pb[((nt * 16 + m) << 4) + (ks << 2) + q];
#pragma unroll
        for (int nt = 0; nt < 8; nt++)
            acc[nt] = __builtin_amdgcn_mfma_f32_16x16x32_f16(af[ks], bf[nt], acc[nt], 0, 0, 0);
    }

    // epilogue: lane owns rows row0 + q*4 + r, col nt*16 + m
    int er = row0 + q * 4;
    float sd[4], ss[4];
#pragma unroll
    for (int r = 0; r < 4; r++) {
        int n = er + r;
        bool ok = n < N_NODES;
        sd[r] = ok ? nd[n] : 0.0f;
        ss[r] = ok ? ns[n] : 0.0f;
    }
#pragma unroll
    for (int nt = 0; nt < 8; nt++) {
        int col = nt * 16 + m;
        float bc = b[col];
#pragma unroll
        for (int r = 0; r < 4; r++) {
            int n = er + r;
            if (n < N_NODES) {
                float v = fmaxf(sd[r] * acc[nt][r] + bc, 0.0f) * ss[r];
                out[(size_t)n * D + col] = __float2half(v);
            }
        }
    }
}

// colsum[c] = sum_n nd[n] * agg16[n][c]
__global__ void k_colsum(const __half* __restrict__ agg, const float* __restrict__ nd,
                         float* __restrict__ colsum) {
    __shared__ float part[128];
    int t = threadIdx.x;
    int c = t & 127, half = t >> 7;
    int chunk = (N_NODES + gridDim.x - 1) / gridDim.x;
    int r0 = blockIdx.x * chunk;
    int r1 = min(r0 + chunk, N_NODES);
    float acc = 0.0f;
    for (int r = r0 + half; r < r1; r += 2)
        acc += nd[r] * __half2float(agg[(size_t)r * D + c]);
    if (half) part[c] = acc;
    __syncthreads();
    if (!half) unsafeAtomicAdd(&colsum[c], acc + part[c]);
}

// out[j] = (colsum/N) @ W2 [:,j] + b2[j]
__global__ void k_final(const float* __restrict__ colsum, const float* __restrict__ W,
                        const float* __restrict__ b, float* __restrict__ out) {
    __shared__ float m[128];
    int j = threadIdx.x;
    m[j] = colsum[j] * (1.0f / N_NODES);
    __syncthreads();
    float acc = b[j];
    for (int k = 0; k < 128; k++)
        acc = fmaf(m[k], W[(size_t)k * D + j], acc);
    out[j] = acc;
}

extern "C" void kernel_launch(void* const* d_in, const int* in_sizes, int n_in,
                              void* d_out, int out_size, void* d_ws, size_t ws_size,
                              hipStream_t stream) {
    const float* h   = (const float*)d_in[0];
    const int*   src = (const int*)d_in[1];
    const int*   dst = (const int*)d_in[2];
    const float* W0  = (const float*)d_in[3];
    const float* b0  = (const float*)d_in[4];
    const float* W1  = (const float*)d_in[5];
    const float* b1  = (const float*)d_in[6];
    const float* W2  = (const float*)d_in[7];
    const float* b2  = (const float*)d_in[8];
    float* out = (float*)d_out;

    // workspace (~60 MB): ppart dead after k_scatter2 -> x16 aliases onto it
    float*        ns      = (float*)d_ws;                       // N
    float*        nd      = ns + N_NODES;                       // N
    float*        colsum  = nd + N_NODES;                       // 128
    int*          row_ptr = (int*)(colsum + 128);               // N+1
    int*          cnt_src = row_ptr + N_NODES + 1;              // N
    int*          cnt_dst = cnt_src + N_NODES;                  // N
    int*          blkSums = cnt_dst + N_NODES;                  // 128
    __half*       Wt16    = (__half*)(blkSums + 128);           // 2*D*D
    int*          csr_src = (int*)(Wt16 + 2 * D * D);           // E
    unsigned int* ppart   = (unsigned int*)(csr_src + N_EDGES); // 2*CHK*PPART_STRIDE
    __half*       x16     = (__half*)ppart;                     // N*D (aliases ppart)
    __half*       agg16   = (__half*)(ppart + 2 * (size_t)CHK * PPART_STRIDE); // N*D

    // ---- CSR build + norms (no global atomics) ----
    k_hist_part<<<8 * CHK, 256, 0, stream>>>(src, dst, ppart);
    k_hist_merge<<<(2 * PPART_STRIDE + 255) / 256, 256, 0, stream>>>(ppart, cnt_src, cnt_dst);
    k_scan1<<<SCAN_NB, 1024, 0, stream>>>(cnt_dst, row_ptr + 1, blkSums);
    k_scan2<<<1, 128, 0, stream>>>(blkSums);
    k_scan3<<<(N_NODES + 255) / 256, 256, 0, stream>>>(row_ptr, blkSums);
    k_norm2<<<(N_NODES + 255) / 256, 256, 0, stream>>>(cnt_src, cnt_dst, ns, nd);
    k_scatter2<<<NSHARD * CHK, 256, 0, stream>>>(src, dst, row_ptr, ppart, csr_src);

    k_prep_w<<<(2 * D * D + 255) / 256, 256, 0, stream>>>(W0, W1, Wt16);
    // x0s = h * ns (fp16; overwrites ppart region — stream-ordered after scatter)
    k_scale_rows<<<(N_NODES * (D / 4) + 255) / 256, 256, 0, stream>>>(h, ns, x16);

    const float* bl[2] = {b0, b1};
    for (int l = 0; l < 3; l++) {
        k_spmm<<<(N_NODES + 3) / 4, 256, 0, stream>>>(x16, row_ptr, csr_src, agg16);
        if (l < 2) {
            k_gemm_mfma<<<(N_NODES + 63) / 64, 256, 0, stream>>>(
                agg16, Wt16 + (size_t)l * D * D, bl[l], nd, ns, x16);
        } else {
            hipMemsetAsync(colsum, 0, 128 * sizeof(float), stream);
            k_colsum<<<256, 256, 0, stream>>>(agg16, nd, colsum);
            k_final<<<1, 128, 0, stream>>>(colsum, W2, b2, out);
        }
    }
}

// Round 6
// 597.991 us; speedup vs baseline: 7.5276x; 1.0096x over previous
//
#include <hip/hip_runtime.h>
#include <hip/hip_fp16.h>

#define N_NODES 100000
#define N_EDGES 1600000
#define D 128
#define SCAN_NB ((N_NODES + 1023) / 1024)   // 98
#define NSHARD 8
#define SH (N_NODES / NSHARD)               // 12500 nodes / scatter shard
#define SH_U (SH / 2)                       // 6250 packed uints
#define CHK 64                              // edge chunks
#define CHUNK_E (N_EDGES / CHK)             // 25000 edges per chunk (<65536 -> 16-bit safe)
#define PAIR_N 25000                        // nodes per hist job (4 jobs cover N)
#define PAIR_U (PAIR_N / 2)                 // 12500 uints = 50 KB LDS
#define PPART_STRIDE (N_NODES / 2)          // 50000 packed uints per (arr,chunk)
#define CS_NB 256                           // colsum partial blocks

typedef _Float16 f16x4 __attribute__((ext_vector_type(4)));
typedef _Float16 f16x8 __attribute__((ext_vector_type(8)));
typedef float f32x4 __attribute__((ext_vector_type(4)));

// ---------------------------------------------------------------------------
// Pass A: LDS-privatized partial histograms, 16-bit packed (2 nodes per uint).
__global__ __launch_bounds__(256) void
k_hist_part(const int* __restrict__ src, const int* __restrict__ dst,
            unsigned int* __restrict__ ppart) {
    __shared__ unsigned int hcnt[PAIR_U];  // 50 KB
    int jb = blockIdx.x >> 6;      // 0..7
    int c  = blockIdx.x & (CHK - 1);
    const int* arr = (jb >> 2) ? dst : src;
    int p  = jb & 3;
    int lo = p * PAIR_N;
    for (int i = threadIdx.x; i < PAIR_U; i += 256) hcnt[i] = 0;
    __syncthreads();
    int e0 = c * CHUNK_E;
    for (int i = e0 + threadIdx.x; i < e0 + CHUNK_E; i += 256) {
        int v = arr[i] - lo;
        if ((unsigned)v < PAIR_N)
            atomicAdd(&hcnt[v >> 1], 1u << ((v & 1) << 4));
    }
    __syncthreads();
    unsigned int* po = ppart + ((size_t)(jb >> 2) * CHK + c) * PPART_STRIDE + p * PAIR_U;
    for (int i = threadIdx.x; i < PAIR_U; i += 256) po[i] = hcnt[i];
}

// Pass B: unpack+sum partials -> cnt; dst partials -> exclusive per-chunk prefix.
__global__ void k_hist_merge(unsigned int* __restrict__ ppart,
                             int* __restrict__ cnt_src, int* __restrict__ cnt_dst) {
    int g = blockIdx.x * blockDim.x + threadIdx.x;  // over 2*PPART_STRIDE
    if (g >= 2 * PPART_STRIDE) return;
    int arr = g / PPART_STRIDE, i = g % PPART_STRIDE;
    unsigned int* p = ppart + (size_t)arr * CHK * PPART_STRIDE + i;
    if (arr == 0) {
        int lo = 0, hi = 0;
#pragma unroll 8
        for (int c = 0; c < CHK; c++) {
            unsigned int u = p[(size_t)c * PPART_STRIDE];
            lo += u & 0xffff; hi += u >> 16;
        }
        cnt_src[2 * i] = lo; cnt_src[2 * i + 1] = hi;
    } else {
        int lo = 0, hi = 0;
#pragma unroll 8
        for (int c = 0; c < CHK; c++) {
            unsigned int u = p[(size_t)c * PPART_STRIDE];
            p[(size_t)c * PPART_STRIDE] = (unsigned)lo | ((unsigned)hi << 16);
            lo += u & 0xffff; hi += u >> 16;
        }
        cnt_dst[2 * i] = lo; cnt_dst[2 * i + 1] = hi;
    }
}

__global__ __launch_bounds__(1024) void
k_scan1(const int* __restrict__ cnt, int* __restrict__ rp1, int* __restrict__ blkSums) {
    __shared__ int s[1024];
    int tid = threadIdx.x;
    int i = blockIdx.x * 1024 + tid;
    int v = (i < N_NODES) ? cnt[i] : 0;
    s[tid] = v;
    __syncthreads();
    for (int d = 1; d < 1024; d <<= 1) {
        int t = (tid >= d) ? s[tid - d] : 0;
        __syncthreads();
        s[tid] += t;
        __syncthreads();
    }
    if (i < N_NODES) rp1[i] = s[tid];
    if (tid == 1023) blkSums[blockIdx.x] = s[1023];
}

__global__ void k_scan2(int* __restrict__ blkSums) {
    __shared__ int s[128];
    int tid = threadIdx.x;
    int v = (tid < SCAN_NB) ? blkSums[tid] : 0;
    s[tid] = v;
    __syncthreads();
    for (int d = 1; d < 128; d <<= 1) {
        int t = (tid >= d) ? s[tid - d] : 0;
        __syncthreads();
        s[tid] += t;
        __syncthreads();
    }
    if (tid < SCAN_NB) blkSums[tid] = s[tid] - v;  // exclusive
}

// fused: finalize row_ptr + compute norms
__global__ void k_scan3norm(int* __restrict__ row_ptr, const int* __restrict__ blkSums,
                            const int* __restrict__ cnt_src, const int* __restrict__ cnt_dst,
                            float* __restrict__ ns, float* __restrict__ nd) {
    int i = blockIdx.x * blockDim.x + threadIdx.x;
    if (i >= N_NODES) return;
    row_ptr[1 + i] += blkSums[i >> 10];
    if (i == 0) row_ptr[0] = 0;
    ns[i] = rsqrtf((float)max(cnt_src[i], 1));
    nd[i] = rsqrtf((float)max(cnt_dst[i], 1));
}

// Pass C: counting-sort scatter (LDS cursors, no global atomics).
__global__ __launch_bounds__(256) void
k_scatter2(const int* __restrict__ src, const int* __restrict__ dst,
           const int* __restrict__ row_ptr, const unsigned int* __restrict__ ppart,
           int* __restrict__ csr_src) {
    __shared__ int cur[SH];  // 50 KB
    int s = blockIdx.x & 7;
    int c = blockIdx.x >> 3;
    int lo = s * SH;
    const unsigned int* pre = ppart + ((size_t)CHK + c) * PPART_STRIDE + s * SH_U;
    for (int t = threadIdx.x; t < SH_U; t += 256) {
        unsigned int u = pre[t];
        cur[2 * t]     = row_ptr[lo + 2 * t]     + (int)(u & 0xffff);
        cur[2 * t + 1] = row_ptr[lo + 2 * t + 1] + (int)(u >> 16);
    }
    __syncthreads();
    int e0 = c * CHUNK_E;
    for (int i = e0 + threadIdx.x; i < e0 + CHUNK_E; i += 256) {
        int d = dst[i] - lo;
        if ((unsigned)d < SH) {
            int pos = atomicAdd(&cur[d], 1);
            csr_src[pos] = src[i];
        }
    }
}

// Wt16[l][n][k] = (half) Wl[k][n]   for l = 0,1
__global__ void k_prep_w(const float* __restrict__ W0, const float* __restrict__ W1,
                         __half* __restrict__ Wt) {
    int i = blockIdx.x * blockDim.x + threadIdx.x;
    if (i >= 2 * D * D) return;
    int l = i >> 14, r = i & (D * D - 1);
    int n = r >> 7, k = r & 127;
    const float* W = l ? W1 : W0;
    Wt[i] = __float2half(W[k * D + n]);
}

// out16[n][:] = x[n][:] * ns[n]
__global__ void k_scale_rows(const float* __restrict__ x, const float* __restrict__ ns,
                             __half* __restrict__ out) {
    int i = blockIdx.x * blockDim.x + threadIdx.x;
    if (i >= N_NODES * (D / 4)) return;
    int n = i >> 5;
    float4 v = ((const float4*)x)[i];
    float s = ns[n];
    ((__half2*)out)[2 * i]     = __floats2half2_rn(v.x * s, v.y * s);
    ((__half2*)out)[2 * i + 1] = __floats2half2_rn(v.z * s, v.w * s);
}

// pull SpMM v2: one wave per node, TWO edges per gather instruction
// (lanes 0-31 -> edge j, lanes 32-63 -> edge j+1; 8B f16x4 per lane = 512B/instr).
// Cross-half shfl_xor reduce at the end; fp32 accum; no atomics.
__global__ __launch_bounds__(256) void
k_spmm(const __half* __restrict__ x, const int* __restrict__ row_ptr,
       const int* __restrict__ csr_src, __half* __restrict__ agg) {
    int wave = (blockIdx.x * blockDim.x + threadIdx.x) >> 6;
    int lane = threadIdx.x & 63;
    int hf = lane >> 5, l32 = lane & 31;
    if (wave >= N_NODES) return;
    int beg = row_ptr[wave], end = row_ptr[wave + 1];
    float a0 = 0.f, a1 = 0.f, a2 = 0.f, a3 = 0.f;
    int j = beg;
    for (; j + 7 < end; j += 8) {
#pragma unroll
        for (int p = 0; p < 4; p++) {
            int s0 = csr_src[j + 2 * p];        // wave-uniform (SMEM path)
            int s1 = csr_src[j + 2 * p + 1];
            int s = hf ? s1 : s0;               // per-half select
            f16x4 v = ((const f16x4*)(x + (size_t)s * D))[l32];
            a0 += (float)v[0]; a1 += (float)v[1]; a2 += (float)v[2]; a3 += (float)v[3];
        }
    }
    for (; j + 1 < end; j += 2) {
        int s0 = csr_src[j], s1 = csr_src[j + 1];
        int s = hf ? s1 : s0;
        f16x4 v = ((const f16x4*)(x + (size_t)s * D))[l32];
        a0 += (float)v[0]; a1 += (float)v[1]; a2 += (float)v[2]; a3 += (float)v[3];
    }
    if (j < end && hf == 0) {
        int s = csr_src[j];
        f16x4 v = ((const f16x4*)(x + (size_t)s * D))[l32];
        a0 += (float)v[0]; a1 += (float)v[1]; a2 += (float)v[2]; a3 += (float)v[3];
    }
    a0 += __shfl_xor(a0, 32, 64);
    a1 += __shfl_xor(a1, 32, 64);
    a2 += __shfl_xor(a2, 32, 64);
    a3 += __shfl_xor(a3, 32, 64);
    if (hf == 0) {
        f16x4 o;
        o[0] = (_Float16)a0; o[1] = (_Float16)a1; o[2] = (_Float16)a2; o[3] = (_Float16)a3;
        ((f16x4*)(agg + (size_t)wave * D))[l32] = o;
    }
}

// MFMA GEMM v2: 32 rows x 128 cols per wave (two A-frag groups share each B frag
// -> Wt L1 traffic halved). mfma_f32_16x16x32_f16, K=128 in 4 steps.
__global__ __launch_bounds__(256) void
k_gemm_mfma(const __half* __restrict__ A, const __half* __restrict__ Wt,
            const float* __restrict__ b, const float* __restrict__ nd,
            const float* __restrict__ ns, __half* __restrict__ out) {
    int w = threadIdx.x >> 6, lane = threadIdx.x & 63;
    int m = lane & 15, q = lane >> 4;
    int row0 = blockIdx.x * 128 + w * 32;   // 32 rows per wave

    f16x8 zf;
#pragma unroll
    for (int j = 0; j < 8; j++) zf[j] = (_Float16)0;
    f16x8 af[2][4];
#pragma unroll
    for (int g = 0; g < 2; g++) {
        int arow = row0 + g * 16 + m;
        const f16x8* pa = (const f16x8*)(A + (size_t)arow * D);
        bool aok = arow < N_NODES;
#pragma unroll
        for (int ks = 0; ks < 4; ks++) af[g][ks] = aok ? pa[ks * 4 + q] : zf;
    }

    const f16x8* pb = (const f16x8*)Wt;
    f32x4 acc[2][8];
#pragma unroll
    for (int g = 0; g < 2; g++)
#pragma unroll
        for (int nt = 0; nt < 8; nt++) acc[g][nt] = (f32x4){0.f, 0.f, 0.f, 0.f};

#pragma unroll
    for (int ks = 0; ks < 4; ks++) {
#pragma unroll
        for (int nt = 0; nt < 8; nt++) {
            f16x8 bf = pb[((nt * 16 + m) << 4) + (ks << 2) + q];
            acc[0][nt] = __builtin_amdgcn_mfma_f32_16x16x32_f16(af[0][ks], bf, acc[0][nt], 0, 0, 0);
            acc[1][nt] = __builtin_amdgcn_mfma_f32_16x16x32_f16(af[1][ks], bf, acc[1][nt], 0, 0, 0);
        }
    }

    // epilogue: D layout col=lane&15, row=q*4+reg
#pragma unroll
    for (int g = 0; g < 2; g++) {
        int er = row0 + g * 16 + q * 4;
        float sd[4], ss[4];
#pragma unroll
        for (int r = 0; r < 4; r++) {
            int n = er + r;
            bool ok = n < N_NODES;
            sd[r] = ok ? nd[n] : 0.0f;
            ss[r] = ok ? ns[n] : 0.0f;
        }
#pragma unroll
        for (int nt = 0; nt < 8; nt++) {
            int col = nt * 16 + m;
            float bc = b[col];
#pragma unroll
            for (int r = 0; r < 4; r++) {
                int n = er + r;
                if (n < N_NODES) {
                    float v = fmaxf(sd[r] * acc[g][nt][r] + bc, 0.0f) * ss[r];
                    out[(size_t)n * D + col] = __float2half(v);
                }
            }
        }
    }
}

// colsum partials: part[blk][c] = sum over this block's rows of nd[n]*agg[n][c]
__global__ void k_colsum(const __half* __restrict__ agg, const float* __restrict__ nd,
                         float* __restrict__ part) {
    __shared__ float sp[128];
    int t = threadIdx.x;
    int c = t & 127, half = t >> 7;
    int chunk = (N_NODES + gridDim.x - 1) / gridDim.x;
    int r0 = blockIdx.x * chunk;
    int r1 = min(r0 + chunk, N_NODES);
    float acc = 0.0f;
    for (int r = r0 + half; r < r1; r += 2)
        acc += nd[r] * __half2float(agg[(size_t)r * D + c]);
    if (half) sp[c] = acc;
    __syncthreads();
    if (!half) part[blockIdx.x * 128 + c] = acc + sp[c];
}

// out[j] = (sum part / N) @ W2 [:,j] + b2[j]
__global__ void k_final(const float* __restrict__ part, const float* __restrict__ W,
                        const float* __restrict__ b, float* __restrict__ out) {
    __shared__ float m[128];
    int j = threadIdx.x;
    float s = 0.0f;
    for (int r = 0; r < CS_NB; r++) s += part[r * 128 + j];
    m[j] = s * (1.0f / N_NODES);
    __syncthreads();
    float acc = b[j];
    for (int k = 0; k < 128; k++)
        acc = fmaf(m[k], W[(size_t)k * D + j], acc);
    out[j] = acc;
}

extern "C" void kernel_launch(void* const* d_in, const int* in_sizes, int n_in,
                              void* d_out, int out_size, void* d_ws, size_t ws_size,
                              hipStream_t stream) {
    const float* h   = (const float*)d_in[0];
    const int*   src = (const int*)d_in[1];
    const int*   dst = (const int*)d_in[2];
    const float* W0  = (const float*)d_in[3];
    const float* b0  = (const float*)d_in[4];
    const float* W1  = (const float*)d_in[5];
    const float* b1  = (const float*)d_in[6];
    const float* W2  = (const float*)d_in[7];
    const float* b2  = (const float*)d_in[8];
    float* out = (float*)d_out;

    // workspace: ppart dead after k_scatter2 -> x16 aliases onto it
    float*        ns      = (float*)d_ws;                       // N
    float*        nd      = ns + N_NODES;                       // N
    float*        cspart  = nd + N_NODES;                       // CS_NB*128
    int*          row_ptr = (int*)(cspart + CS_NB * 128);       // N+1
    int*          cnt_src = row_ptr + N_NODES + 1;              // N
    int*          cnt_dst = cnt_src + N_NODES;                  // N
    int*          blkSums = cnt_dst + N_NODES;                  // 128
    __half*       Wt16    = (__half*)(blkSums + 128);           // 2*D*D
    int*          csr_src = (int*)(Wt16 + 2 * D * D);           // E
    unsigned int* ppart   = (unsigned int*)(csr_src + N_EDGES); // 2*CHK*PPART_STRIDE
    __half*       x16     = (__half*)ppart;                     // N*D (aliases ppart)
    __half*       agg16   = (__half*)(ppart + 2 * (size_t)CHK * PPART_STRIDE); // N*D

    // ---- CSR build + norms (no global atomics) ----
    k_hist_part<<<8 * CHK, 256, 0, stream>>>(src, dst, ppart);
    k_hist_merge<<<(2 * PPART_STRIDE + 255) / 256, 256, 0, stream>>>(ppart, cnt_src, cnt_dst);
    k_scan1<<<SCAN_NB, 1024, 0, stream>>>(cnt_dst, row_ptr + 1, blkSums);
    k_scan2<<<1, 128, 0, stream>>>(blkSums);
    k_scan3norm<<<(N_NODES + 255) / 256, 256, 0, stream>>>(row_ptr, blkSums,
                                                           cnt_src, cnt_dst, ns, nd);
    k_scatter2<<<NSHARD * CHK, 256, 0, stream>>>(src, dst, row_ptr, ppart, csr_src);

    k_prep_w<<<(2 * D * D + 255) / 256, 256, 0, stream>>>(W0, W1, Wt16);
    k_scale_rows<<<(N_NODES * (D / 4) + 255) / 256, 256, 0, stream>>>(h, ns, x16);

    const float* bl[2] = {b0, b1};
    for (int l = 0; l < 3; l++) {
        k_spmm<<<(N_NODES + 3) / 4, 256, 0, stream>>>(x16, row_ptr, csr_src, agg16);
        if (l < 2) {
            k_gemm_mfma<<<(N_NODES + 127) / 128, 256, 0, stream>>>(
                agg16, Wt16 + (size_t)l * D * D, bl[l], nd, ns, x16);
        } else {
            k_colsum<<<CS_NB, 256, 0, stream>>>(agg16, nd, cspart);
            k_final<<<1, 128, 0, stream>>>(cspart, W2, b2, out);
        }
    }
}

// Round 7
// 537.675 us; speedup vs baseline: 8.3720x; 1.1122x over previous
//
#include <hip/hip_runtime.h>
#include <hip/hip_fp16.h>

#define N_NODES 100000
#define N_EDGES 1600000
#define D 128
#define SCAN_NB ((N_NODES + 1023) / 1024)   // 98
#define CHK 64                              // edge chunks
#define CHUNK_E (N_EDGES / CHK)             // 25000 edges/chunk
#define HALF_N 50000                        // hist: nodes per half
#define HALF_U (HALF_N / 4)                 // 12500 uints (8-bit packed, 50 KB LDS)
#define PP_STRIDE (N_NODES / 4)             // 25000 uints per (arr,chunk)
#define NSH4 4                              // scatter shards
#define SH4 (N_NODES / NSH4)                // 25000 nodes/shard
#define SH4_U (SH4 / 4)                     // 6250 uints (25 KB LDS)

typedef _Float16 f16x4 __attribute__((ext_vector_type(4)));
typedef _Float16 f16x8 __attribute__((ext_vector_type(8)));
typedef float f32x4 __attribute__((ext_vector_type(4)));

// ---------------------------------------------------------------------------
// Pass A: LDS histograms, 8-bit packed (4 nodes/uint; per-chunk count << 255).
// block = (arr, half, chunk); 256 blocks; reads each array only 2x.
__global__ __launch_bounds__(256) void
k_hist(const int* __restrict__ src, const int* __restrict__ dst,
       unsigned int* __restrict__ pp) {
    __shared__ unsigned int h[HALF_U];  // 50 KB
    int b = blockIdx.x;
    int arr = b >> 7, half = (b >> 6) & 1, c = b & (CHK - 1);
    const int* a = arr ? dst : src;
    int lo = half * HALF_N;
    for (int i = threadIdx.x; i < HALF_U; i += 256) h[i] = 0;
    __syncthreads();
    int e0 = c * CHUNK_E;
    for (int i = e0 + threadIdx.x; i < e0 + CHUNK_E; i += 256) {
        int v = a[i] - lo;
        if ((unsigned)v < HALF_N)
            atomicAdd(&h[v >> 2], 1u << ((v & 3) * 8));
    }
    __syncthreads();
    unsigned int* po = pp + ((size_t)(arr * CHK + c)) * PP_STRIDE + half * HALF_U;
    for (int i = threadIdx.x; i < HALF_U; i += 256) po[i] = h[i];
}

// Pass B: per-node totals -> cnt_{src,dst}; partials -> exclusive per-chunk
// prefix (8-bit packed, prefix <= degree < 256), in place, BOTH arrays.
__global__ void k_merge(unsigned int* __restrict__ pp,
                        int* __restrict__ cnt_src, int* __restrict__ cnt_dst) {
    int g = blockIdx.x * blockDim.x + threadIdx.x;  // over 2*PP_STRIDE
    if (g >= 2 * PP_STRIDE) return;
    int arr = g / PP_STRIDE, u = g % PP_STRIDE;
    unsigned int* p = pp + ((size_t)arr * CHK) * PP_STRIDE + u;
    int s0 = 0, s1 = 0, s2 = 0, s3 = 0;
#pragma unroll 8
    for (int c = 0; c < CHK; c++) {
        unsigned int v = p[(size_t)c * PP_STRIDE];
        p[(size_t)c * PP_STRIDE] =
            (unsigned)s0 | ((unsigned)s1 << 8) | ((unsigned)s2 << 16) | ((unsigned)s3 << 24);
        s0 += v & 255; s1 += (v >> 8) & 255; s2 += (v >> 16) & 255; s3 += (v >> 24) & 255;
    }
    int* cnt = arr ? cnt_dst : cnt_src;
    cnt[4 * u + 0] = s0; cnt[4 * u + 1] = s1; cnt[4 * u + 2] = s2; cnt[4 * u + 3] = s3;
}

// scan both cnt arrays: blocks [0,98) -> dst/row_ptr, [98,196) -> src/row_ptr2
__global__ __launch_bounds__(1024) void
k_scan1(const int* __restrict__ cnt_dst, const int* __restrict__ cnt_src,
        int* __restrict__ rpD, int* __restrict__ rpS,
        int* __restrict__ bsD, int* __restrict__ bsS) {
    __shared__ int s[1024];
    int arr = blockIdx.x / SCAN_NB, bb = blockIdx.x % SCAN_NB;
    const int* cnt = arr ? cnt_src : cnt_dst;
    int* rp1 = (arr ? rpS : rpD) + 1;
    int* bs = arr ? bsS : bsD;
    int tid = threadIdx.x;
    int i = bb * 1024 + tid;
    int v = (i < N_NODES) ? cnt[i] : 0;
    s[tid] = v;
    __syncthreads();
    for (int d = 1; d < 1024; d <<= 1) {
        int t = (tid >= d) ? s[tid - d] : 0;
        __syncthreads();
        s[tid] += t;
        __syncthreads();
    }
    if (i < N_NODES) rp1[i] = s[tid];
    if (tid == 1023) bs[bb] = s[1023];
}

__global__ void k_scan2(int* __restrict__ bsD, int* __restrict__ bsS) {
    __shared__ int s[128];
    int* bs = blockIdx.x ? bsS : bsD;
    int tid = threadIdx.x;
    int v = (tid < SCAN_NB) ? bs[tid] : 0;
    s[tid] = v;
    __syncthreads();
    for (int d = 1; d < 128; d <<= 1) {
        int t = (tid >= d) ? s[tid - d] : 0;
        __syncthreads();
        s[tid] += t;
        __syncthreads();
    }
    if (tid < SCAN_NB) bs[tid] = s[tid] - v;  // exclusive
}

// finalize both row_ptrs + norms
__global__ void k_scan3norm(int* __restrict__ rpD, int* __restrict__ rpS,
                            const int* __restrict__ bsD, const int* __restrict__ bsS,
                            const int* __restrict__ cnt_src, const int* __restrict__ cnt_dst,
                            float* __restrict__ ns, float* __restrict__ nd) {
    int i = blockIdx.x * blockDim.x + threadIdx.x;
    if (i >= N_NODES) return;
    rpD[1 + i] += bsD[i >> 10];
    rpS[1 + i] += bsS[i >> 10];
    if (i == 0) { rpD[0] = 0; rpS[0] = 0; }
    ns[i] = rsqrtf((float)max(cnt_src[i], 1));
    nd[i] = rsqrtf((float)max(cnt_dst[i], 1));
}

// Pass C1: counting-sort by dst, payload src. LDS 8-bit rank counters;
// pos = row_ptr[d] + pre8[c][d] + rank. No global atomics.
__global__ __launch_bounds__(256) void
k_scatter_dst(const int* __restrict__ src, const int* __restrict__ dst,
              const int* __restrict__ rpD, const unsigned int* __restrict__ pp,
              int* __restrict__ csr_src) {
    __shared__ unsigned int cur[SH4_U];  // 25 KB
    int sh = blockIdx.x & 3, c = blockIdx.x >> 2;
    int lo = sh * SH4;
    const unsigned int* pre = pp + ((size_t)(CHK + c)) * PP_STRIDE;  // arr=1 (dst)
    for (int i = threadIdx.x; i < SH4_U; i += 256) cur[i] = 0;
    __syncthreads();
    int e0 = c * CHUNK_E;
    for (int i = e0 + threadIdx.x; i < e0 + CHUNK_E; i += 256) {
        int dfull = dst[i];
        int d = dfull - lo;
        if ((unsigned)d < SH4) {
            int sft = (d & 3) * 8;
            int rank = (atomicAdd(&cur[d >> 2], 1u << sft) >> sft) & 255;
            int p8 = (pre[dfull >> 2] >> ((dfull & 3) * 8)) & 255;
            csr_src[rpD[dfull] + p8 + rank] = src[i];
        }
    }
}

// Pass C2: counting-sort by src, payload nd[dst] (float) -> csrv.
__global__ __launch_bounds__(256) void
k_scatter_src(const int* __restrict__ src, const int* __restrict__ dst,
              const int* __restrict__ rpS, const unsigned int* __restrict__ pp,
              const float* __restrict__ nd, float* __restrict__ csrv) {
    __shared__ unsigned int cur[SH4_U];  // 25 KB
    int sh = blockIdx.x & 3, c = blockIdx.x >> 2;
    int lo = sh * SH4;
    const unsigned int* pre = pp + (size_t)c * PP_STRIDE;  // arr=0 (src)
    for (int i = threadIdx.x; i < SH4_U; i += 256) cur[i] = 0;
    __syncthreads();
    int e0 = c * CHUNK_E;
    for (int i = e0 + threadIdx.x; i < e0 + CHUNK_E; i += 256) {
        int sfull = src[i];
        int s = sfull - lo;
        if ((unsigned)s < SH4) {
            int sft = (s & 3) * 8;
            int rank = (atomicAdd(&cur[s >> 2], 1u << sft) >> sft) & 255;
            int p8 = (pre[sfull >> 2] >> ((sfull & 3) * 8)) & 255;
            csrv[rpS[sfull] + p8 + rank] = nd[dst[i]];
        }
    }
}

// wsum[n] = ns[n] * sum of csrv over n's src-list (4 lanes per node)
__global__ void k_wsum(const int* __restrict__ rpS, const float* __restrict__ csrv,
                       const float* __restrict__ ns, float* __restrict__ wsum) {
    int gid = blockIdx.x * blockDim.x + threadIdx.x;
    int wv = gid >> 6, lane = gid & 63;
    int n = wv * 16 + (lane & 15);
    int off = lane >> 4;
    float s = 0.0f;
    int beg = 0, end = 0;
    if (n < N_NODES) { beg = rpS[n]; end = rpS[n + 1]; }
    for (int j = beg + off; j < end; j += 4) s += csrv[j];
    s += __shfl_xor(s, 16, 64);
    s += __shfl_xor(s, 32, 64);
    if (n < N_NODES && lane < 16) wsum[n] = s * ns[n];
}

// Wt16[l][n][k] = (half) Wl[k][n]   for l = 0,1
__global__ void k_prep_w(const float* __restrict__ W0, const float* __restrict__ W1,
                         __half* __restrict__ Wt) {
    int i = blockIdx.x * blockDim.x + threadIdx.x;
    if (i >= 2 * D * D) return;
    int l = i >> 14, r = i & (D * D - 1);
    int n = r >> 7, k = r & 127;
    const float* W = l ? W1 : W0;
    Wt[i] = __float2half(W[k * D + n]);
}

// out16[n][:] = x[n][:] * ns[n]
__global__ void k_scale_rows(const float* __restrict__ x, const float* __restrict__ ns,
                             __half* __restrict__ out) {
    int i = blockIdx.x * blockDim.x + threadIdx.x;
    if (i >= N_NODES * (D / 4)) return;
    int n = i >> 5;
    float4 v = ((const float4*)x)[i];
    float s = ns[n];
    ((__half2*)out)[2 * i]     = __floats2half2_rn(v.x * s, v.y * s);
    ((__half2*)out)[2 * i + 1] = __floats2half2_rn(v.z * s, v.w * s);
}

// pull SpMM: one wave per node, 2 edges per gather instruction.
__global__ __launch_bounds__(256) void
k_spmm(const __half* __restrict__ x, const int* __restrict__ row_ptr,
       const int* __restrict__ csr_src, __half* __restrict__ agg) {
    int wave = (blockIdx.x * blockDim.x + threadIdx.x) >> 6;
    int lane = threadIdx.x & 63;
    int hf = lane >> 5, l32 = lane & 31;
    if (wave >= N_NODES) return;
    int beg = row_ptr[wave], end = row_ptr[wave + 1];
    float a0 = 0.f, a1 = 0.f, a2 = 0.f, a3 = 0.f;
    int j = beg;
    for (; j + 7 < end; j += 8) {
#pragma unroll
        for (int p = 0; p < 4; p++) {
            int s0 = csr_src[j + 2 * p];
            int s1 = csr_src[j + 2 * p + 1];
            int s = hf ? s1 : s0;
            f16x4 v = ((const f16x4*)(x + (size_t)s * D))[l32];
            a0 += (float)v[0]; a1 += (float)v[1]; a2 += (float)v[2]; a3 += (float)v[3];
        }
    }
    for (; j + 1 < end; j += 2) {
        int s0 = csr_src[j], s1 = csr_src[j + 1];
        int s = hf ? s1 : s0;
        f16x4 v = ((const f16x4*)(x + (size_t)s * D))[l32];
        a0 += (float)v[0]; a1 += (float)v[1]; a2 += (float)v[2]; a3 += (float)v[3];
    }
    if (j < end && hf == 0) {
        int s = csr_src[j];
        f16x4 v = ((const f16x4*)(x + (size_t)s * D))[l32];
        a0 += (float)v[0]; a1 += (float)v[1]; a2 += (float)v[2]; a3 += (float)v[3];
    }
    a0 += __shfl_xor(a0, 32, 64);
    a1 += __shfl_xor(a1, 32, 64);
    a2 += __shfl_xor(a2, 32, 64);
    a3 += __shfl_xor(a3, 32, 64);
    if (hf == 0) {
        f16x4 o;
        o[0] = (_Float16)a0; o[1] = (_Float16)a1; o[2] = (_Float16)a2; o[3] = (_Float16)a3;
        ((f16x4*)(agg + (size_t)wave * D))[l32] = o;
    }
}

// MFMA GEMM (layer 1): 32 rows x 128 cols per wave; stores fp16 rows.
__global__ __launch_bounds__(256) void
k_gemm_mfma(const __half* __restrict__ A, const __half* __restrict__ Wt,
            const float* __restrict__ b, const float* __restrict__ nd,
            const float* __restrict__ ns, __half* __restrict__ out) {
    int w = threadIdx.x >> 6, lane = threadIdx.x & 63;
    int m = lane & 15, q = lane >> 4;
    int row0 = blockIdx.x * 128 + w * 32;

    f16x8 zf;
#pragma unroll
    for (int j = 0; j < 8; j++) zf[j] = (_Float16)0;
    f16x8 af[2][4];
#pragma unroll
    for (int g = 0; g < 2; g++) {
        int arow = row0 + g * 16 + m;
        const f16x8* pa = (const f16x8*)(A + (size_t)arow * D);
        bool aok = arow < N_NODES;
#pragma unroll
        for (int ks = 0; ks < 4; ks++) af[g][ks] = aok ? pa[ks * 4 + q] : zf;
    }

    const f16x8* pb = (const f16x8*)Wt;
    f32x4 acc[2][8];
#pragma unroll
    for (int g = 0; g < 2; g++)
#pragma unroll
        for (int nt = 0; nt < 8; nt++) acc[g][nt] = (f32x4){0.f, 0.f, 0.f, 0.f};

#pragma unroll
    for (int ks = 0; ks < 4; ks++) {
#pragma unroll
        for (int nt = 0; nt < 8; nt++) {
            f16x8 bf = pb[((nt * 16 + m) << 4) + (ks << 2) + q];
            acc[0][nt] = __builtin_amdgcn_mfma_f32_16x16x32_f16(af[0][ks], bf, acc[0][nt], 0, 0, 0);
            acc[1][nt] = __builtin_amdgcn_mfma_f32_16x16x32_f16(af[1][ks], bf, acc[1][nt], 0, 0, 0);
        }
    }

#pragma unroll
    for (int g = 0; g < 2; g++) {
        int er = row0 + g * 16 + q * 4;
        float sd[4], ss[4];
#pragma unroll
        for (int r = 0; r < 4; r++) {
            int n = er + r;
            bool ok = n < N_NODES;
            sd[r] = ok ? nd[n] : 0.0f;
            ss[r] = ok ? ns[n] : 0.0f;
        }
#pragma unroll
        for (int nt = 0; nt < 8; nt++) {
            int col = nt * 16 + m;
            float bc = b[col];
#pragma unroll
            for (int r = 0; r < 4; r++) {
                int n = er + r;
                if (n < N_NODES) {
                    float v = fmaxf(sd[r] * acc[g][nt][r] + bc, 0.0f) * ss[r];
                    out[(size_t)n * D + col] = __float2half(v);
                }
            }
        }
    }
}

// MFMA GEMM (layer 2, fused final reduction):
// colsum[col] += sum_n wsum[n] * relu(nd[n]*(A@W1)[n][col] + b1[col])
// (wsum pre-multiplied by ns). No row stores.
__global__ __launch_bounds__(256) void
k_gemm_red(const __half* __restrict__ A, const __half* __restrict__ Wt,
           const float* __restrict__ b, const float* __restrict__ nd,
           const float* __restrict__ wsum, float* __restrict__ colsum) {
    __shared__ float red[128];
    int tid = threadIdx.x;
    if (tid < 128) red[tid] = 0.0f;
    __syncthreads();

    int w = tid >> 6, lane = tid & 63;
    int m = lane & 15, q = lane >> 4;
    int row0 = blockIdx.x * 128 + w * 32;

    f16x8 zf;
#pragma unroll
    for (int j = 0; j < 8; j++) zf[j] = (_Float16)0;
    f16x8 af[2][4];
#pragma unroll
    for (int g = 0; g < 2; g++) {
        int arow = row0 + g * 16 + m;
        const f16x8* pa = (const f16x8*)(A + (size_t)arow * D);
        bool aok = arow < N_NODES;
#pragma unroll
        for (int ks = 0; ks < 4; ks++) af[g][ks] = aok ? pa[ks * 4 + q] : zf;
    }

    const f16x8* pb = (const f16x8*)Wt;
    f32x4 acc[2][8];
#pragma unroll
    for (int g = 0; g < 2; g++)
#pragma unroll
        for (int nt = 0; nt < 8; nt++) acc[g][nt] = (f32x4){0.f, 0.f, 0.f, 0.f};

#pragma unroll
    for (int ks = 0; ks < 4; ks++) {
#pragma unroll
        for (int nt = 0; nt < 8; nt++) {
            f16x8 bf = pb[((nt * 16 + m) << 4) + (ks << 2) + q];
            acc[0][nt] = __builtin_amdgcn_mfma_f32_16x16x32_f16(af[0][ks], bf, acc[0][nt], 0, 0, 0);
            acc[1][nt] = __builtin_amdgcn_mfma_f32_16x16x32_f16(af[1][ks], bf, acc[1][nt], 0, 0, 0);
        }
    }

    float sd[2][4], sw[2][4];
#pragma unroll
    for (int g = 0; g < 2; g++) {
        int er = row0 + g * 16 + q * 4;
#pragma unroll
        for (int r = 0; r < 4; r++) {
            int n = er + r;
            bool ok = n < N_NODES;
            sd[g][r] = ok ? nd[n] : 0.0f;
            sw[g][r] = ok ? wsum[n] : 0.0f;
        }
    }
#pragma unroll
    for (int nt = 0; nt < 8; nt++) {
        int col = nt * 16 + m;
        float bc = b[col];
        float pc = 0.0f;
#pragma unroll
        for (int g = 0; g < 2; g++)
#pragma unroll
            for (int r = 0; r < 4; r++)
                pc += sw[g][r] * fmaxf(sd[g][r] * acc[g][nt][r] + bc, 0.0f);
        atomicAdd(&red[col], pc);
    }
    __syncthreads();
    if (tid < 128) unsafeAtomicAdd(&colsum[tid], red[tid]);
}

// out[j] = (colsum/N) @ W2 [:,j] + b2[j]
__global__ void k_final(const float* __restrict__ colsum, const float* __restrict__ W,
                        const float* __restrict__ b, float* __restrict__ out) {
    __shared__ float m[128];
    int j = threadIdx.x;
    m[j] = colsum[j] * (1.0f / N_NODES);
    __syncthreads();
    float acc = b[j];
    for (int k = 0; k < 128; k++)
        acc = fmaf(m[k], W[(size_t)k * D + j], acc);
    out[j] = acc;
}

extern "C" void kernel_launch(void* const* d_in, const int* in_sizes, int n_in,
                              void* d_out, int out_size, void* d_ws, size_t ws_size,
                              hipStream_t stream) {
    const float* h   = (const float*)d_in[0];
    const int*   src = (const int*)d_in[1];
    const int*   dst = (const int*)d_in[2];
    const float* W0  = (const float*)d_in[3];
    const float* b0  = (const float*)d_in[4];
    const float* W1  = (const float*)d_in[5];
    const float* b1  = (const float*)d_in[6];
    const float* W2  = (const float*)d_in[7];
    const float* b2  = (const float*)d_in[8];
    float* out = (float*)d_out;

    // workspace (~67 MB); pp dead after scatters -> x16 aliases onto it
    float*        ns      = (float*)d_ws;                       // N
    float*        nd      = ns + N_NODES;                       // N
    float*        wsum    = nd + N_NODES;                       // N
    float*        colsum  = wsum + N_NODES;                     // 128
    int*          rpD     = (int*)(colsum + 128);               // N+1
    int*          rpS     = rpD + N_NODES + 1;                  // N+1
    int*          cnt_src = rpS + N_NODES + 1;                  // N
    int*          cnt_dst = cnt_src + N_NODES;                  // N
    int*          bsD     = cnt_dst + N_NODES;                  // 128
    int*          bsS     = bsD + 128;                          // 128
    __half*       Wt16    = (__half*)(bsS + 128);               // 2*D*D
    int*          csr_src = (int*)(Wt16 + 2 * D * D);           // E
    float*        csrv    = (float*)(csr_src + N_EDGES);        // E
    unsigned int* pp      = (unsigned int*)(csrv + N_EDGES);    // 2*CHK*PP_STRIDE (12.8MB)
    __half*       x16     = (__half*)pp;                        // N*D (25.6MB, aliases pp)
    __half*       agg16   = x16 + (size_t)N_NODES * D;          // N*D

    // ---- CSR build (both directions) + norms + wsum; no global atomics ----
    k_hist<<<2 * 2 * CHK, 256, 0, stream>>>(src, dst, pp);
    k_merge<<<(2 * PP_STRIDE + 255) / 256, 256, 0, stream>>>(pp, cnt_src, cnt_dst);
    k_scan1<<<2 * SCAN_NB, 1024, 0, stream>>>(cnt_dst, cnt_src, rpD, rpS, bsD, bsS);
    k_scan2<<<2, 128, 0, stream>>>(bsD, bsS);
    k_scan3norm<<<(N_NODES + 255) / 256, 256, 0, stream>>>(rpD, rpS, bsD, bsS,
                                                           cnt_src, cnt_dst, ns, nd);
    k_scatter_dst<<<NSH4 * CHK, 256, 0, stream>>>(src, dst, rpD, pp, csr_src);
    k_scatter_src<<<NSH4 * CHK, 256, 0, stream>>>(src, dst, rpS, pp, nd, csrv);
    k_wsum<<<(N_NODES * 4 + 255) / 256, 256, 0, stream>>>(rpS, csrv, ns, wsum);

    k_prep_w<<<(2 * D * D + 255) / 256, 256, 0, stream>>>(W0, W1, Wt16);
    // x0s = h * ns (fp16; overwrites pp region — stream-ordered after scatters)
    k_scale_rows<<<(N_NODES * (D / 4) + 255) / 256, 256, 0, stream>>>(h, ns, x16);
    hipMemsetAsync(colsum, 0, 128 * sizeof(float), stream);

    // layer 0
    k_spmm<<<(N_NODES + 3) / 4, 256, 0, stream>>>(x16, rpD, csr_src, agg16);
    k_gemm_mfma<<<(N_NODES + 127) / 128, 256, 0, stream>>>(agg16, Wt16, b0, nd, ns, x16);
    // layer 1 + fused layer-2 reduction
    k_spmm<<<(N_NODES + 3) / 4, 256, 0, stream>>>(x16, rpD, csr_src, agg16);
    k_gemm_red<<<(N_NODES + 127) / 128, 256, 0, stream>>>(agg16, Wt16 + (size_t)D * D,
                                                          b1, nd, wsum, colsum);
    k_final<<<1, 128, 0, stream>>>(colsum, W2, b2, out);
}

// Round 8
// 439.016 us; speedup vs baseline: 10.2534x; 1.2247x over previous
//
#include <hip/hip_runtime.h>
#include <hip/hip_fp16.h>

#define N_NODES 100000
#define N_EDGES 1600000
#define D 128
#define SCAN_NB ((N_NODES + 1023) / 1024)   // 98
#define CHK 128                             // edge chunks
#define CHUNK_E (N_EDGES / CHK)             // 12500 edges/chunk (per-node count << 255)
#define HALF_N 50000                        // hist: nodes per half
#define HALF_U (HALF_N / 4)                 // 12500 uints (8-bit packed, 50 KB LDS)
#define PP_STRIDE (N_NODES / 4)             // 25000 uints per (arr,chunk)
#define NSH4 4                              // scatter shards
#define SH4 (N_NODES / NSH4)                // 25000 nodes/shard
#define SH4_U (SH4 / 4)                     // 6250 uints (25 KB LDS)

typedef _Float16 f16x4 __attribute__((ext_vector_type(4)));
typedef _Float16 f16x8 __attribute__((ext_vector_type(8)));
typedef float f32x4 __attribute__((ext_vector_type(4)));
typedef float f32x2 __attribute__((ext_vector_type(2)));

// ---------------------------------------------------------------------------
// Pass A: LDS histograms, 8-bit packed (4 nodes/uint).
// block = (arr, half, chunk); 512 blocks; reads each index array 2x.
__global__ __launch_bounds__(256) void
k_hist(const int* __restrict__ src, const int* __restrict__ dst,
       unsigned int* __restrict__ pp) {
    __shared__ unsigned int h[HALF_U];  // 50 KB
    int b = blockIdx.x;
    int arr = b >> 8, half = (b >> 7) & 1, c = b & (CHK - 1);
    const int* a = arr ? dst : src;
    int lo = half * HALF_N;
    for (int i = threadIdx.x; i < HALF_U; i += 256) h[i] = 0;
    __syncthreads();
    int e0 = c * CHUNK_E;
    for (int i = e0 + threadIdx.x; i < e0 + CHUNK_E; i += 256) {
        int v = a[i] - lo;
        if ((unsigned)v < HALF_N)
            atomicAdd(&h[v >> 2], 1u << ((v & 3) * 8));
    }
    __syncthreads();
    unsigned int* po = pp + ((size_t)(arr * CHK + c)) * PP_STRIDE + half * HALF_U;
    for (int i = threadIdx.x; i < HALF_U; i += 256) po[i] = h[i];
}

// Pass B: per-node totals -> cnt_{src,dst}; partials -> exclusive per-chunk
// prefix (8-bit packed), in place, BOTH arrays.
__global__ void k_merge(unsigned int* __restrict__ pp,
                        int* __restrict__ cnt_src, int* __restrict__ cnt_dst) {
    int g = blockIdx.x * blockDim.x + threadIdx.x;  // over 2*PP_STRIDE
    if (g >= 2 * PP_STRIDE) return;
    int arr = g / PP_STRIDE, u = g % PP_STRIDE;
    unsigned int* p = pp + ((size_t)arr * CHK) * PP_STRIDE + u;
    int s0 = 0, s1 = 0, s2 = 0, s3 = 0;
#pragma unroll 8
    for (int c = 0; c < CHK; c++) {
        unsigned int v = p[(size_t)c * PP_STRIDE];
        p[(size_t)c * PP_STRIDE] =
            (unsigned)s0 | ((unsigned)s1 << 8) | ((unsigned)s2 << 16) | ((unsigned)s3 << 24);
        s0 += v & 255; s1 += (v >> 8) & 255; s2 += (v >> 16) & 255; s3 += (v >> 24) & 255;
    }
    int* cnt = arr ? cnt_dst : cnt_src;
    cnt[4 * u + 0] = s0; cnt[4 * u + 1] = s1; cnt[4 * u + 2] = s2; cnt[4 * u + 3] = s3;
}

// scan both cnt arrays
__global__ __launch_bounds__(1024) void
k_scan1(const int* __restrict__ cnt_dst, const int* __restrict__ cnt_src,
        int* __restrict__ rpD, int* __restrict__ rpS,
        int* __restrict__ bsD, int* __restrict__ bsS) {
    __shared__ int s[1024];
    int arr = blockIdx.x / SCAN_NB, bb = blockIdx.x % SCAN_NB;
    const int* cnt = arr ? cnt_src : cnt_dst;
    int* rp1 = (arr ? rpS : rpD) + 1;
    int* bs = arr ? bsS : bsD;
    int tid = threadIdx.x;
    int i = bb * 1024 + tid;
    int v = (i < N_NODES) ? cnt[i] : 0;
    s[tid] = v;
    __syncthreads();
    for (int d = 1; d < 1024; d <<= 1) {
        int t = (tid >= d) ? s[tid - d] : 0;
        __syncthreads();
        s[tid] += t;
        __syncthreads();
    }
    if (i < N_NODES) rp1[i] = s[tid];
    if (tid == 1023) bs[bb] = s[1023];
}

__global__ void k_scan2(int* __restrict__ bsD, int* __restrict__ bsS) {
    __shared__ int s[128];
    int* bs = blockIdx.x ? bsS : bsD;
    int tid = threadIdx.x;
    int v = (tid < SCAN_NB) ? bs[tid] : 0;
    s[tid] = v;
    __syncthreads();
    for (int d = 1; d < 128; d <<= 1) {
        int t = (tid >= d) ? s[tid - d] : 0;
        __syncthreads();
        s[tid] += t;
        __syncthreads();
    }
    if (tid < SCAN_NB) bs[tid] = s[tid] - v;  // exclusive
}

// finalize both row_ptrs + norms
__global__ void k_scan3norm(int* __restrict__ rpD, int* __restrict__ rpS,
                            const int* __restrict__ bsD, const int* __restrict__ bsS,
                            const int* __restrict__ cnt_src, const int* __restrict__ cnt_dst,
                            float* __restrict__ ns, float* __restrict__ nd) {
    int i = blockIdx.x * blockDim.x + threadIdx.x;
    if (i >= N_NODES) return;
    rpD[1 + i] += bsD[i >> 10];
    rpS[1 + i] += bsS[i >> 10];
    if (i == 0) { rpD[0] = 0; rpS[0] = 0; }
    ns[i] = rsqrtf((float)max(cnt_src[i], 1));
    nd[i] = rsqrtf((float)max(cnt_dst[i], 1));
}

// Pass C1: counting-sort by dst, payload src (LDS 8-bit rank counters).
__global__ __launch_bounds__(256) void
k_scatter_dst(const int* __restrict__ src, const int* __restrict__ dst,
              const int* __restrict__ rpD, const unsigned int* __restrict__ pp,
              int* __restrict__ csr_src) {
    __shared__ unsigned int cur[SH4_U];  // 25 KB
    int sh = blockIdx.x & 3, c = blockIdx.x >> 2;
    int lo = sh * SH4;
    const unsigned int* pre = pp + ((size_t)(CHK + c)) * PP_STRIDE;  // arr=1 (dst)
    for (int i = threadIdx.x; i < SH4_U; i += 256) cur[i] = 0;
    __syncthreads();
    int e0 = c * CHUNK_E;
    for (int i = e0 + threadIdx.x; i < e0 + CHUNK_E; i += 256) {
        int dfull = dst[i];
        int d = dfull - lo;
        if ((unsigned)d < SH4) {
            int sft = (d & 3) * 8;
            int rank = (atomicAdd(&cur[d >> 2], 1u << sft) >> sft) & 255;
            int p8 = (pre[dfull >> 2] >> ((dfull & 3) * 8)) & 255;
            csr_src[rpD[dfull] + p8 + rank] = src[i];
        }
    }
}

// Pass C2: counting-sort by src, payload nd[dst] -> csrv.
__global__ __launch_bounds__(256) void
k_scatter_src(const int* __restrict__ src, const int* __restrict__ dst,
              const int* __restrict__ rpS, const unsigned int* __restrict__ pp,
              const float* __restrict__ nd, float* __restrict__ csrv) {
    __shared__ unsigned int cur[SH4_U];  // 25 KB
    int sh = blockIdx.x & 3, c = blockIdx.x >> 2;
    int lo = sh * SH4;
    const unsigned int* pre = pp + (size_t)c * PP_STRIDE;  // arr=0 (src)
    for (int i = threadIdx.x; i < SH4_U; i += 256) cur[i] = 0;
    __syncthreads();
    int e0 = c * CHUNK_E;
    for (int i = e0 + threadIdx.x; i < e0 + CHUNK_E; i += 256) {
        int sfull = src[i];
        int s = sfull - lo;
        if ((unsigned)s < SH4) {
            int sft = (s & 3) * 8;
            int rank = (atomicAdd(&cur[s >> 2], 1u << sft) >> sft) & 255;
            int p8 = (pre[sfull >> 2] >> ((sfull & 3) * 8)) & 255;
            csrv[rpS[sfull] + p8 + rank] = nd[dst[i]];
        }
    }
}

// wsum[n] = ns[n] * sum of csrv over n's src-list (4 lanes per node)
__global__ void k_wsum(const int* __restrict__ rpS, const float* __restrict__ csrv,
                       const float* __restrict__ ns, float* __restrict__ wsum) {
    int gid = blockIdx.x * blockDim.x + threadIdx.x;
    int wv = gid >> 6, lane = gid & 63;
    int n = wv * 16 + (lane & 15);
    int off = lane >> 4;
    float s = 0.0f;
    int beg = 0, end = 0;
    if (n < N_NODES) { beg = rpS[n]; end = rpS[n + 1]; }
    for (int j = beg + off; j < end; j += 4) s += csrv[j];
    s += __shfl_xor(s, 16, 64);
    s += __shfl_xor(s, 32, 64);
    if (n < N_NODES && lane < 16) wsum[n] = s * ns[n];
}

// Wt16[l][n][k] = (half) Wl[k][n]   for l = 0,1
__global__ void k_prep_w(const float* __restrict__ W0, const float* __restrict__ W1,
                         __half* __restrict__ Wt) {
    int i = blockIdx.x * blockDim.x + threadIdx.x;
    if (i >= 2 * D * D) return;
    int l = i >> 14, r = i & (D * D - 1);
    int n = r >> 7, k = r & 127;
    const float* W = l ? W1 : W0;
    Wt[i] = __float2half(W[k * D + n]);
}

// x8[n][:] = fp8_e4m3( x[n][:] * ns[n] )   (HW cvt_pk_fp8)
__global__ void k_scale_rows(const float* __restrict__ x, const float* __restrict__ ns,
                             unsigned int* __restrict__ out) {
    int i = blockIdx.x * blockDim.x + threadIdx.x;  // over N*D/4
    if (i >= N_NODES * (D / 4)) return;
    int n = i >> 5;
    float4 v = ((const float4*)x)[i];
    float s = ns[n];
    int u = __builtin_amdgcn_cvt_pk_fp8_f32(v.x * s, v.y * s, 0, false);
    u = __builtin_amdgcn_cvt_pk_fp8_f32(v.z * s, v.w * s, u, true);
    out[i] = (unsigned int)u;
}

// pull SpMM (fp8 gather -> fp32 accum -> fp16 agg): one wave per node,
// 2 edges per gather instruction (lane reads uint = 4 fp8; 32 lanes/row).
__global__ __launch_bounds__(256) void
k_spmm(const unsigned char* __restrict__ x8, const int* __restrict__ row_ptr,
       const int* __restrict__ csr_src, __half* __restrict__ agg) {
    int wave = (blockIdx.x * blockDim.x + threadIdx.x) >> 6;
    int lane = threadIdx.x & 63;
    int hf = lane >> 5, l32 = lane & 31;
    if (wave >= N_NODES) return;
    int beg = row_ptr[wave], end = row_ptr[wave + 1];
    float a0 = 0.f, a1 = 0.f, a2 = 0.f, a3 = 0.f;
    int j = beg;
    for (; j + 7 < end; j += 8) {
#pragma unroll
        for (int p = 0; p < 4; p++) {
            int s0 = csr_src[j + 2 * p];
            int s1 = csr_src[j + 2 * p + 1];
            int s = hf ? s1 : s0;
            unsigned int u = *(const unsigned int*)(x8 + (size_t)s * D + 4 * l32);
            f32x2 lo = __builtin_amdgcn_cvt_pk_f32_fp8(u, false);
            f32x2 hi = __builtin_amdgcn_cvt_pk_f32_fp8(u, true);
            a0 += lo[0]; a1 += lo[1]; a2 += hi[0]; a3 += hi[1];
        }
    }
    for (; j + 1 < end; j += 2) {
        int s0 = csr_src[j], s1 = csr_src[j + 1];
        int s = hf ? s1 : s0;
        unsigned int u = *(const unsigned int*)(x8 + (size_t)s * D + 4 * l32);
        f32x2 lo = __builtin_amdgcn_cvt_pk_f32_fp8(u, false);
        f32x2 hi = __builtin_amdgcn_cvt_pk_f32_fp8(u, true);
        a0 += lo[0]; a1 += lo[1]; a2 += hi[0]; a3 += hi[1];
    }
    if (j < end && hf == 0) {
        int s = csr_src[j];
        unsigned int u = *(const unsigned int*)(x8 + (size_t)s * D + 4 * l32);
        f32x2 lo = __builtin_amdgcn_cvt_pk_f32_fp8(u, false);
        f32x2 hi = __builtin_amdgcn_cvt_pk_f32_fp8(u, true);
        a0 += lo[0]; a1 += lo[1]; a2 += hi[0]; a3 += hi[1];
    }
    a0 += __shfl_xor(a0, 32, 64);
    a1 += __shfl_xor(a1, 32, 64);
    a2 += __shfl_xor(a2, 32, 64);
    a3 += __shfl_xor(a3, 32, 64);
    if (hf == 0) {
        f16x4 o;
        o[0] = (_Float16)a0; o[1] = (_Float16)a1; o[2] = (_Float16)a2; o[3] = (_Float16)a3;
        ((f16x4*)(agg + (size_t)wave * D))[l32] = o;
    }
}

// MFMA GEMM (layer 0): A fp16 (agg), out fp8 rows (pre-scaled by ns for next spmm).
__global__ __launch_bounds__(256) void
k_gemm_mfma(const __half* __restrict__ A, const __half* __restrict__ Wt,
            const float* __restrict__ b, const float* __restrict__ nd,
            const float* __restrict__ ns, unsigned char* __restrict__ out) {
    int w = threadIdx.x >> 6, lane = threadIdx.x & 63;
    int m = lane & 15, q = lane >> 4;
    int row0 = blockIdx.x * 128 + w * 32;

    f16x8 zf;
#pragma unroll
    for (int j = 0; j < 8; j++) zf[j] = (_Float16)0;
    f16x8 af[2][4];
#pragma unroll
    for (int g = 0; g < 2; g++) {
        int arow = row0 + g * 16 + m;
        const f16x8* pa = (const f16x8*)(A + (size_t)arow * D);
        bool aok = arow < N_NODES;
#pragma unroll
        for (int ks = 0; ks < 4; ks++) af[g][ks] = aok ? pa[ks * 4 + q] : zf;
    }

    const f16x8* pb = (const f16x8*)Wt;
    f32x4 acc[2][8];
#pragma unroll
    for (int g = 0; g < 2; g++)
#pragma unroll
        for (int nt = 0; nt < 8; nt++) acc[g][nt] = (f32x4){0.f, 0.f, 0.f, 0.f};

#pragma unroll
    for (int ks = 0; ks < 4; ks++) {
#pragma unroll
        for (int nt = 0; nt < 8; nt++) {
            f16x8 bf = pb[((nt * 16 + m) << 4) + (ks << 2) + q];
            acc[0][nt] = __builtin_amdgcn_mfma_f32_16x16x32_f16(af[0][ks], bf, acc[0][nt], 0, 0, 0);
            acc[1][nt] = __builtin_amdgcn_mfma_f32_16x16x32_f16(af[1][ks], bf, acc[1][nt], 0, 0, 0);
        }
    }

#pragma unroll
    for (int g = 0; g < 2; g++) {
        int er = row0 + g * 16 + q * 4;
        float sd[4], ss[4];
#pragma unroll
        for (int r = 0; r < 4; r++) {
            int n = er + r;
            bool ok = n < N_NODES;
            sd[r] = ok ? nd[n] : 0.0f;
            ss[r] = ok ? ns[n] : 0.0f;
        }
#pragma unroll
        for (int nt = 0; nt < 8; nt++) {
            int col = nt * 16 + m;
            float bc = b[col];
#pragma unroll
            for (int r = 0; r < 4; r++) {
                int n = er + r;
                if (n < N_NODES) {
                    float v = fmaxf(sd[r] * acc[g][nt][r] + bc, 0.0f) * ss[r];
                    int pk = __builtin_amdgcn_cvt_pk_fp8_f32(v, v, 0, false);
                    out[(size_t)n * D + col] = (unsigned char)(pk & 0xff);
                }
            }
        }
    }
}

// MFMA GEMM (layer 1 + fused final reduction):
// colsum[col] += sum_n wsum[n] * relu(nd[n]*(A@W1)[n][col] + b1[col])
__global__ __launch_bounds__(256) void
k_gemm_red(const __half* __restrict__ A, const __half* __restrict__ Wt,
           const float* __restrict__ b, const float* __restrict__ nd,
           const float* __restrict__ wsum, float* __restrict__ colsum) {
    __shared__ float red[128];
    int tid = threadIdx.x;
    if (tid < 128) red[tid] = 0.0f;
    __syncthreads();

    int w = tid >> 6, lane = tid & 63;
    int m = lane & 15, q = lane >> 4;
    int row0 = blockIdx.x * 128 + w * 32;

    f16x8 zf;
#pragma unroll
    for (int j = 0; j < 8; j++) zf[j] = (_Float16)0;
    f16x8 af[2][4];
#pragma unroll
    for (int g = 0; g < 2; g++) {
        int arow = row0 + g * 16 + m;
        const f16x8* pa = (const f16x8*)(A + (size_t)arow * D);
        bool aok = arow < N_NODES;
#pragma unroll
        for (int ks = 0; ks < 4; ks++) af[g][ks] = aok ? pa[ks * 4 + q] : zf;
    }

    const f16x8* pb = (const f16x8*)Wt;
    f32x4 acc[2][8];
#pragma unroll
    for (int g = 0; g < 2; g++)
#pragma unroll
        for (int nt = 0; nt < 8; nt++) acc[g][nt] = (f32x4){0.f, 0.f, 0.f, 0.f};

#pragma unroll
    for (int ks = 0; ks < 4; ks++) {
#pragma unroll
        for (int nt = 0; nt < 8; nt++) {
            f16x8 bf = pb[((nt * 16 + m) << 4) + (ks << 2) + q];
            acc[0][nt] = __builtin_amdgcn_mfma_f32_16x16x32_f16(af[0][ks], bf, acc[0][nt], 0, 0, 0);
            acc[1][nt] = __builtin_amdgcn_mfma_f32_16x16x32_f16(af[1][ks], bf, acc[1][nt], 0, 0, 0);
        }
    }

    float sd[2][4], sw[2][4];
#pragma unroll
    for (int g = 0; g < 2; g++) {
        int er = row0 + g * 16 + q * 4;
#pragma unroll
        for (int r = 0; r < 4; r++) {
            int n = er + r;
            bool ok = n < N_NODES;
            sd[g][r] = ok ? nd[n] : 0.0f;
            sw[g][r] = ok ? wsum[n] : 0.0f;
        }
    }
#pragma unroll
    for (int nt = 0; nt < 8; nt++) {
        int col = nt * 16 + m;
        float bc = b[col];
        float pc = 0.0f;
#pragma unroll
        for (int g = 0; g < 2; g++)
#pragma unroll
            for (int r = 0; r < 4; r++)
                pc += sw[g][r] * fmaxf(sd[g][r] * acc[g][nt][r] + bc, 0.0f);
        atomicAdd(&red[col], pc);
    }
    __syncthreads();
    if (tid < 128) unsafeAtomicAdd(&colsum[tid], red[tid]);
}

// out[j] = (colsum/N) @ W2 [:,j] + b2[j]
__global__ void k_final(const float* __restrict__ colsum, const float* __restrict__ W,
                        const float* __restrict__ b, float* __restrict__ out) {
    __shared__ float m[128];
    int j = threadIdx.x;
    m[j] = colsum[j] * (1.0f / N_NODES);
    __syncthreads();
    float acc = b[j];
    for (int k = 0; k < 128; k++)
        acc = fmaf(m[k], W[(size_t)k * D + j], acc);
    out[j] = acc;
}

extern "C" void kernel_launch(void* const* d_in, const int* in_sizes, int n_in,
                              void* d_out, int out_size, void* d_ws, size_t ws_size,
                              hipStream_t stream) {
    const float* h   = (const float*)d_in[0];
    const int*   src = (const int*)d_in[1];
    const int*   dst = (const int*)d_in[2];
    const float* W0  = (const float*)d_in[3];
    const float* b0  = (const float*)d_in[4];
    const float* W1  = (const float*)d_in[5];
    const float* b1  = (const float*)d_in[6];
    const float* W2  = (const float*)d_in[7];
    const float* b2  = (const float*)d_in[8];
    float* out = (float*)d_out;

    // workspace (~70 MB); pp (25.6 MB) dead after scatters -> x8 (12.8 MB) aliases it
    float*         ns      = (float*)d_ws;                       // N
    float*         nd      = ns + N_NODES;                       // N
    float*         wsum    = nd + N_NODES;                       // N
    float*         colsum  = wsum + N_NODES;                     // 128
    int*           rpD     = (int*)(colsum + 128);               // N+1
    int*           rpS     = rpD + N_NODES + 1;                  // N+1
    int*           cnt_src = rpS + N_NODES + 1;                  // N
    int*           cnt_dst = cnt_src + N_NODES;                  // N
    int*           bsD     = cnt_dst + N_NODES;                  // 128
    int*           bsS     = bsD + 128;                          // 128
    __half*        Wt16    = (__half*)(bsS + 128);               // 2*D*D
    int*           csr_src = (int*)(Wt16 + 2 * D * D);           // E
    float*         csrv    = (float*)(csr_src + N_EDGES);        // E
    unsigned int*  pp      = (unsigned int*)(csrv + N_EDGES);    // 2*CHK*PP_STRIDE (25.6MB)
    unsigned char* x8      = (unsigned char*)pp;                 // N*D fp8 (12.8MB, aliases pp)
    __half*        agg16   = (__half*)(pp + 2 * (size_t)CHK * PP_STRIDE); // N*D fp16

    // ---- CSR build (both directions) + norms + wsum; no global atomics ----
    k_hist<<<2 * 2 * CHK, 256, 0, stream>>>(src, dst, pp);
    k_merge<<<(2 * PP_STRIDE + 255) / 256, 256, 0, stream>>>(pp, cnt_src, cnt_dst);
    k_scan1<<<2 * SCAN_NB, 1024, 0, stream>>>(cnt_dst, cnt_src, rpD, rpS, bsD, bsS);
    k_scan2<<<2, 128, 0, stream>>>(bsD, bsS);
    k_scan3norm<<<(N_NODES + 255) / 256, 256, 0, stream>>>(rpD, rpS, bsD, bsS,
                                                           cnt_src, cnt_dst, ns, nd);
    k_scatter_dst<<<NSH4 * CHK, 256, 0, stream>>>(src, dst, rpD, pp, csr_src);
    k_scatter_src<<<NSH4 * CHK, 256, 0, stream>>>(src, dst, rpS, pp, nd, csrv);
    k_wsum<<<(N_NODES * 4 + 255) / 256, 256, 0, stream>>>(rpS, csrv, ns, wsum);

    k_prep_w<<<(2 * D * D + 255) / 256, 256, 0, stream>>>(W0, W1, Wt16);
    // x0 = fp8(h * ns)  (overwrites pp region — stream-ordered after scatters)
    k_scale_rows<<<(N_NODES * (D / 4) + 255) / 256, 256, 0, stream>>>(h, ns, (unsigned int*)x8);
    hipMemsetAsync(colsum, 0, 128 * sizeof(float), stream);

    // layer 0
    k_spmm<<<(N_NODES + 3) / 4, 256, 0, stream>>>(x8, rpD, csr_src, agg16);
    k_gemm_mfma<<<(N_NODES + 127) / 128, 256, 0, stream>>>(agg16, Wt16, b0, nd, ns, x8);
    // layer 1 + fused layer-2 reduction
    k_spmm<<<(N_NODES + 3) / 4, 256, 0, stream>>>(x8, rpD, csr_src, agg16);
    k_gemm_red<<<(N_NODES + 127) / 128, 256, 0, stream>>>(agg16, Wt16 + (size_t)D * D,
                                                          b1, nd, wsum, colsum);
    k_final<<<1, 128, 0, stream>>>(colsum, W2, b2, out);
}